// Round 1
// baseline (3568.759 us; speedup 1.0000x reference)
//
#include <hip/hip_runtime.h>

constexpr int N_USER = 100000;
constexpr int N_ITEM = 200000;
constexpr int N_ALL  = N_USER + N_ITEM;
constexpr int E_UI   = 3200000;
constexpr int E_UU   = 1600000;
constexpr int D      = 64;

// Copy concatenated (user_emb, item_emb) into emb buffer AND ui_sum output.
__global__ void init_ui_kernel(const float* __restrict__ ue,
                               const float* __restrict__ ie,
                               float* __restrict__ emb,
                               float* __restrict__ ui_sum) {
    long t = (long)blockIdx.x * blockDim.x + threadIdx.x;
    const long total = (long)N_ALL * D;
    if (t >= total) return;
    const long userN = (long)N_USER * D;
    float v = (t < userN) ? ue[t] : ie[t - userN];
    emb[t] = v;
    ui_sum[t] = v;
}

// Copy user_emb into emb buffer AND uu_sum output.
__global__ void init_uu_kernel(const float* __restrict__ ue,
                               float* __restrict__ emb,
                               float* __restrict__ uu_sum) {
    long t = (long)blockIdx.x * blockDim.x + threadIdx.x;
    const long total = (long)N_USER * D;
    if (t >= total) return;
    float v = ue[t];
    emb[t] = v;
    uu_sum[t] = v;
}

// Count in/out degrees with float atomics (counts are small ints, exact in f32).
__global__ void count_deg_kernel(const int* __restrict__ src,
                                 const int* __restrict__ dst,
                                 int E,
                                 float* __restrict__ deg_out,
                                 float* __restrict__ deg_in) {
    int e = blockIdx.x * blockDim.x + threadIdx.x;
    if (e >= E) return;
    atomicAdd(&deg_out[src[e]], 1.0f);
    atomicAdd(&deg_in[dst[e]], 1.0f);
}

// In-place deg -> clip(deg,1)^-0.5 for both arrays.
__global__ void rsq_kernel(float* __restrict__ a, float* __restrict__ b, int n) {
    int i = blockIdx.x * blockDim.x + threadIdx.x;
    if (i >= n) return;
    a[i] = 1.0f / sqrtf(fmaxf(a[i], 1.0f));
    b[i] = 1.0f / sqrtf(fmaxf(b[i], 1.0f));
}

// One wave (64 lanes) per edge: agg[dst] += emb[src] * rsq_out[src]
__global__ void edge_scatter_kernel(const int* __restrict__ src,
                                    const int* __restrict__ dst,
                                    const float* __restrict__ emb,
                                    const float* __restrict__ rsq_out,
                                    float* __restrict__ agg,
                                    int E) {
    int wave = blockIdx.x * (blockDim.x >> 6) + (threadIdx.x >> 6);
    int lane = threadIdx.x & 63;
    if (wave >= E) return;
    int s = src[wave];
    int d = dst[wave];
    float v = emb[s * D + lane] * rsq_out[s];
    atomicAdd(&agg[d * D + lane], v);
}

// One wave per row: scale by rsq_in, LeakyReLU(0.5), L2-normalize (wave
// reduction), accumulate into sum_out, write new emb.
__global__ void finalize_kernel(const float* __restrict__ agg,
                                const float* __restrict__ rsq_in,
                                float* __restrict__ emb,
                                float* __restrict__ sum_out,
                                int n) {
    int row = blockIdx.x * (blockDim.x >> 6) + (threadIdx.x >> 6);
    int lane = threadIdx.x & 63;
    if (row >= n) return;
    float v = agg[row * D + lane] * rsq_in[row];
    v = (v > 0.0f) ? v : 0.5f * v;      // LeakyReLU(negative_slope=0.5)
    float ss = v * v;
    #pragma unroll
    for (int m = 32; m >= 1; m >>= 1) ss += __shfl_xor(ss, m, 64);
    float denom = fmaxf(sqrtf(ss), 1e-12f);
    sum_out[row * D + lane] += v / denom;
    emb[row * D + lane] = v;
}

extern "C" void kernel_launch(void* const* d_in, const int* in_sizes, int n_in,
                              void* d_out, int out_size, void* d_ws, size_t ws_size,
                              hipStream_t stream) {
    const float* user_emb = (const float*)d_in[0];
    const float* item_emb = (const float*)d_in[1];
    const int*   ui_src   = (const int*)d_in[2];
    const int*   ui_dst   = (const int*)d_in[3];
    const int*   uu_src   = (const int*)d_in[4];
    const int*   uu_dst   = (const int*)d_in[5];

    float* out    = (float*)d_out;
    float* ui_sum = out;                         // [N_ALL * D]
    float* uu_sum = out + (size_t)N_ALL * D;     // [N_USER * D]

    char* ws = (char*)d_ws;
    float* emb = (float*)ws;       ws += (size_t)N_ALL * D * sizeof(float);
    float* agg = (float*)ws;       ws += (size_t)N_ALL * D * sizeof(float);
    float* rsq_out = (float*)ws;   ws += (size_t)N_ALL * sizeof(float);
    float* rsq_in  = (float*)ws;   ws += (size_t)N_ALL * sizeof(float);

    const int BLK = 256;
    const int WPB = BLK / 64;  // waves per block

    // ---------------- user-item graph (N_ALL nodes, 3 layers) ----------------
    {
        long tot = (long)N_ALL * D;
        init_ui_kernel<<<(int)((tot + BLK - 1) / BLK), BLK, 0, stream>>>(
            user_emb, item_emb, emb, ui_sum);

        hipMemsetAsync(rsq_out, 0, (size_t)N_ALL * sizeof(float), stream);
        hipMemsetAsync(rsq_in,  0, (size_t)N_ALL * sizeof(float), stream);
        count_deg_kernel<<<(E_UI + BLK - 1) / BLK, BLK, 0, stream>>>(
            ui_src, ui_dst, E_UI, rsq_out, rsq_in);
        rsq_kernel<<<(N_ALL + BLK - 1) / BLK, BLK, 0, stream>>>(rsq_out, rsq_in, N_ALL);

        for (int l = 0; l < 3; ++l) {
            hipMemsetAsync(agg, 0, (size_t)N_ALL * D * sizeof(float), stream);
            edge_scatter_kernel<<<(E_UI + WPB - 1) / WPB, BLK, 0, stream>>>(
                ui_src, ui_dst, emb, rsq_out, agg, E_UI);
            finalize_kernel<<<(N_ALL + WPB - 1) / WPB, BLK, 0, stream>>>(
                agg, rsq_in, emb, ui_sum, N_ALL);
        }
    }

    // ---------------- user-user graph (N_USER nodes, 2 layers) ----------------
    {
        long tot = (long)N_USER * D;
        init_uu_kernel<<<(int)((tot + BLK - 1) / BLK), BLK, 0, stream>>>(
            user_emb, emb, uu_sum);

        hipMemsetAsync(rsq_out, 0, (size_t)N_USER * sizeof(float), stream);
        hipMemsetAsync(rsq_in,  0, (size_t)N_USER * sizeof(float), stream);
        count_deg_kernel<<<(E_UU + BLK - 1) / BLK, BLK, 0, stream>>>(
            uu_src, uu_dst, E_UU, rsq_out, rsq_in);
        rsq_kernel<<<(N_USER + BLK - 1) / BLK, BLK, 0, stream>>>(rsq_out, rsq_in, N_USER);

        for (int l = 0; l < 2; ++l) {
            hipMemsetAsync(agg, 0, (size_t)N_USER * D * sizeof(float), stream);
            edge_scatter_kernel<<<(E_UU + WPB - 1) / WPB, BLK, 0, stream>>>(
                uu_src, uu_dst, emb, rsq_out, agg, E_UU);
            finalize_kernel<<<(N_USER + WPB - 1) / WPB, BLK, 0, stream>>>(
                agg, rsq_in, emb, uu_sum, N_USER);
        }
    }
}

// Round 2
// 1464.481 us; speedup vs baseline: 2.4369x; 2.4369x over previous
//
#include <hip/hip_runtime.h>

constexpr int N_USER = 100000;
constexpr int N_ITEM = 200000;
constexpr int N_ALL  = N_USER + N_ITEM;
constexpr int E_UI   = 3200000;
constexpr int E_UU   = 1600000;
constexpr int D      = 64;
constexpr int BLK    = 256;

// ---------------- small helpers ----------------

__device__ inline int wave_incl_scan(int x, int lane) {
    #pragma unroll
    for (int off = 1; off < 64; off <<= 1) {
        int y = __shfl_up(x, off, 64);
        if (lane >= off) x += y;
    }
    return x;
}

// ---------------- init kernels ----------------

// emb_scaled = concat(ue,ie) * rsq_out[row];  ui_sum = concat(ue,ie)
__global__ void init_ui_kernel(const float* __restrict__ ue,
                               const float* __restrict__ ie,
                               const float* __restrict__ rsq_out,
                               float* __restrict__ emb_scaled,
                               float* __restrict__ ui_sum) {
    size_t t = (size_t)blockIdx.x * blockDim.x + threadIdx.x;
    const size_t total = (size_t)N_ALL * D;
    if (t >= total) return;
    const size_t userN = (size_t)N_USER * D;
    float v = (t < userN) ? ue[t] : ie[t - userN];
    int row = (int)(t >> 6);
    emb_scaled[t] = v * rsq_out[row];
    ui_sum[t] = v;
}

__global__ void init_uu_kernel(const float* __restrict__ ue,
                               const float* __restrict__ rsq_out,
                               float* __restrict__ emb_scaled,
                               float* __restrict__ uu_sum) {
    size_t t = (size_t)blockIdx.x * blockDim.x + threadIdx.x;
    const size_t total = (size_t)N_USER * D;
    if (t >= total) return;
    float v = ue[t];
    int row = (int)(t >> 6);
    emb_scaled[t] = v * rsq_out[row];
    uu_sum[t] = v;
}

// ---------------- degree / CSR build ----------------

__global__ void hist_kernel(const int* __restrict__ src,
                            const int* __restrict__ dst, int E,
                            int* __restrict__ cnt_out,
                            int* __restrict__ cnt_in) {
    int e = blockIdx.x * blockDim.x + threadIdx.x;
    if (e >= E) return;
    atomicAdd(&cnt_out[src[e]], 1);
    atomicAdd(&cnt_in[dst[e]], 1);
}

__global__ void rsq_from_cnt_kernel(const int* __restrict__ co,
                                    const int* __restrict__ ci,
                                    float* __restrict__ ro,
                                    float* __restrict__ ri, int n) {
    int i = blockIdx.x * blockDim.x + threadIdx.x;
    if (i >= n) return;
    ro[i] = 1.0f / sqrtf(fmaxf((float)co[i], 1.0f));
    ri[i] = 1.0f / sqrtf(fmaxf((float)ci[i], 1.0f));
}

// exclusive scan of cnt[0..n) -> row_ptr[1..n] (local inclusive), blk_sums[b]=block total
__global__ void scan1_kernel(const int* __restrict__ cnt,
                             int* __restrict__ row_ptr,
                             int* __restrict__ blk_sums, int n) {
    int i = blockIdx.x * BLK + threadIdx.x;
    int lane = threadIdx.x & 63, wid = threadIdx.x >> 6;
    int x = (i < n) ? cnt[i] : 0;
    int s = wave_incl_scan(x, lane);
    __shared__ int wsum[4];
    if (lane == 63) wsum[wid] = s;
    __syncthreads();
    int add = 0;
    for (int w = 0; w < wid; ++w) add += wsum[w];
    s += add;
    if (i < n) row_ptr[i + 1] = s;
    if (threadIdx.x == BLK - 1) blk_sums[blockIdx.x] = s;
}

// in-place exclusive scan of blk_sums[0..nb), single block
__global__ void scan2_kernel(int* __restrict__ data, int nb) {
    __shared__ int wsum[4];
    __shared__ int carry_s;
    int lane = threadIdx.x & 63, wid = threadIdx.x >> 6;
    if (threadIdx.x == 0) carry_s = 0;
    for (int base = 0; base < nb; base += BLK) {
        __syncthreads();
        int i = base + threadIdx.x;
        int x = (i < nb) ? data[i] : 0;
        int s = wave_incl_scan(x, lane);
        if (lane == 63) wsum[wid] = s;
        __syncthreads();
        int add = carry_s;
        for (int w = 0; w < wid; ++w) add += wsum[w];
        int excl = add + s - x;
        if (i < nb) data[i] = excl;
        int total = wsum[0] + wsum[1] + wsum[2] + wsum[3];
        __syncthreads();
        if (threadIdx.x == 0) carry_s = add + total;  // add==old carry for t0
    }
}

__global__ void scan3_kernel(int* __restrict__ row_ptr,
                             const int* __restrict__ blk_offs, int n) {
    int i = blockIdx.x * BLK + threadIdx.x;
    if (i < n) row_ptr[i + 1] += blk_offs[blockIdx.x];
    if (i == 0) row_ptr[0] = 0;
}

__global__ void copy_int_kernel(const int* __restrict__ a, int* __restrict__ b, int n) {
    int i = blockIdx.x * blockDim.x + threadIdx.x;
    if (i < n) b[i] = a[i];
}

__global__ void build_csr_kernel(const int* __restrict__ src,
                                 const int* __restrict__ dst, int E,
                                 int* __restrict__ cursor,
                                 int* __restrict__ col) {
    int e = blockIdx.x * blockDim.x + threadIdx.x;
    if (e >= E) return;
    int pos = atomicAdd(&cursor[dst[e]], 1);
    col[pos] = src[e];
}

// ---------------- fused GCN layer (gather, no atomics) ----------------
// One wave per destination row:
//   acc = sum_{s in N_in(row)} emb_in[s]          (emb_in pre-scaled by rsq_out)
//   v   = LeakyReLU_{0.5}(acc * rsq_in[row])
//   sum_out[row] += v / max(||v||, 1e-12)
//   emb_out[row]  = v * rsq_out[row]              (pre-scale for next layer)
__global__ void gcn_layer_kernel(const int* __restrict__ row_ptr,
                                 const int* __restrict__ col,
                                 const float* __restrict__ emb_in,
                                 const float* __restrict__ rsq_in,
                                 const float* __restrict__ rsq_out,
                                 float* __restrict__ sum_out,
                                 float* __restrict__ emb_out,
                                 int n) {
    int row = blockIdx.x * (blockDim.x >> 6) + (threadIdx.x >> 6);
    int lane = threadIdx.x & 63;
    if (row >= n) return;
    int beg = row_ptr[row], end = row_ptr[row + 1];
    float acc = 0.f;
    for (int c = beg; c < end; c += 64) {
        int m = min(64, end - c);
        int sidx = (c + lane < end) ? col[c + lane] : 0;
        int j = 0;
        for (; j + 4 <= m; j += 4) {
            int s0 = __shfl(sidx, j, 64);
            int s1 = __shfl(sidx, j + 1, 64);
            int s2 = __shfl(sidx, j + 2, 64);
            int s3 = __shfl(sidx, j + 3, 64);
            float a0 = emb_in[(size_t)s0 * D + lane];
            float a1 = emb_in[(size_t)s1 * D + lane];
            float a2 = emb_in[(size_t)s2 * D + lane];
            float a3 = emb_in[(size_t)s3 * D + lane];
            acc += a0; acc += a1; acc += a2; acc += a3;
        }
        for (; j < m; ++j) {
            int s = __shfl(sidx, j, 64);
            acc += emb_in[(size_t)s * D + lane];
        }
    }
    float v = acc * rsq_in[row];
    v = (v > 0.f) ? v : 0.5f * v;  // LeakyReLU(0.5)
    float ss = v * v;
    #pragma unroll
    for (int mm = 32; mm >= 1; mm >>= 1) ss += __shfl_xor(ss, mm, 64);
    float denom = fmaxf(sqrtf(ss), 1e-12f);
    size_t o = (size_t)row * D + lane;
    sum_out[o] += v / denom;
    emb_out[o] = v * rsq_out[row];
}

// ---------------- host side ----------------

static inline int cdiv(int a, int b) { return (a + b - 1) / b; }

struct CsrBufs {
    int *cnt_out, *cnt_in, *row_ptr, *cursor, *col, *blk_sums;
    float *rsq_out, *rsq_in;
};

static void build_graph(const int* src, const int* dst, int E, int n,
                        CsrBufs& B, hipStream_t stream) {
    hipMemsetAsync(B.cnt_out, 0, (size_t)n * sizeof(int), stream);
    hipMemsetAsync(B.cnt_in,  0, (size_t)n * sizeof(int), stream);
    hist_kernel<<<cdiv(E, BLK), BLK, 0, stream>>>(src, dst, E, B.cnt_out, B.cnt_in);
    rsq_from_cnt_kernel<<<cdiv(n, BLK), BLK, 0, stream>>>(B.cnt_out, B.cnt_in,
                                                          B.rsq_out, B.rsq_in, n);
    int nb = cdiv(n, BLK);
    scan1_kernel<<<nb, BLK, 0, stream>>>(B.cnt_in, B.row_ptr, B.blk_sums, n);
    scan2_kernel<<<1, BLK, 0, stream>>>(B.blk_sums, nb);
    scan3_kernel<<<nb, BLK, 0, stream>>>(B.row_ptr, B.blk_sums, n);
    copy_int_kernel<<<cdiv(n, BLK), BLK, 0, stream>>>(B.row_ptr, B.cursor, n);
    build_csr_kernel<<<cdiv(E, BLK), BLK, 0, stream>>>(src, dst, E, B.cursor, B.col);
}

extern "C" void kernel_launch(void* const* d_in, const int* in_sizes, int n_in,
                              void* d_out, int out_size, void* d_ws, size_t ws_size,
                              hipStream_t stream) {
    const float* user_emb = (const float*)d_in[0];
    const float* item_emb = (const float*)d_in[1];
    const int*   ui_src   = (const int*)d_in[2];
    const int*   ui_dst   = (const int*)d_in[3];
    const int*   uu_src   = (const int*)d_in[4];
    const int*   uu_dst   = (const int*)d_in[5];

    float* out    = (float*)d_out;
    float* ui_sum = out;                          // [N_ALL * D]
    float* uu_sum = out + (size_t)N_ALL * D;      // [N_USER * D]

    // ws: two ping-pong emb buffers (pre-scaled by rsq_out)
    float* embA = (float*)d_ws;
    float* embB = embA + (size_t)N_ALL * D;

    // UI CSR scratch lives in the uu_sum region of d_out (dead during UI phase).
    // Budget 25.6 MB; we use ~20.0 MB.
    {
        char* p = (char*)uu_sum;
        CsrBufs UI;
        UI.col      = (int*)p;            p += (size_t)E_UI * sizeof(int);
        UI.row_ptr  = (int*)p;            p += (size_t)(N_ALL + 1) * sizeof(int);
        UI.cursor   = (int*)p;            p += (size_t)N_ALL * sizeof(int);
        UI.cnt_out  = (int*)p;            p += (size_t)N_ALL * sizeof(int);
        UI.cnt_in   = (int*)p;            p += (size_t)N_ALL * sizeof(int);
        UI.rsq_out  = (float*)p;          p += (size_t)N_ALL * sizeof(float);
        UI.rsq_in   = (float*)p;          p += (size_t)N_ALL * sizeof(float);
        UI.blk_sums = (int*)p;            p += 8192;

        build_graph(ui_src, ui_dst, E_UI, N_ALL, UI, stream);

        size_t tot = (size_t)N_ALL * D;
        init_ui_kernel<<<cdiv((int)tot, BLK), BLK, 0, stream>>>(
            user_emb, item_emb, UI.rsq_out, embA, ui_sum);

        float* bufs[2] = {embA, embB};
        for (int l = 0; l < 3; ++l) {
            gcn_layer_kernel<<<cdiv(N_ALL, BLK / 64), BLK, 0, stream>>>(
                UI.row_ptr, UI.col, bufs[l & 1], UI.rsq_in, UI.rsq_out,
                ui_sum, bufs[(l + 1) & 1], N_ALL);
        }
    }

    // UU CSR scratch lives in the upper (unused) part of embA: UU layers only
    // touch the first N_USER rows (25.6 MB) of each emb buffer. Budget 51.2 MB;
    // we use ~8.8 MB.
    {
        char* p = (char*)(embA + (size_t)N_USER * D);
        CsrBufs UU;
        UU.col      = (int*)p;            p += (size_t)E_UU * sizeof(int);
        UU.row_ptr  = (int*)p;            p += (size_t)(N_USER + 1) * sizeof(int);
        UU.cursor   = (int*)p;            p += (size_t)N_USER * sizeof(int);
        UU.cnt_out  = (int*)p;            p += (size_t)N_USER * sizeof(int);
        UU.cnt_in   = (int*)p;            p += (size_t)N_USER * sizeof(int);
        UU.rsq_out  = (float*)p;          p += (size_t)N_USER * sizeof(float);
        UU.rsq_in   = (float*)p;          p += (size_t)N_USER * sizeof(float);
        UU.blk_sums = (int*)p;            p += 8192;

        build_graph(uu_src, uu_dst, E_UU, N_USER, UU, stream);

        size_t tot = (size_t)N_USER * D;
        init_uu_kernel<<<cdiv((int)tot, BLK), BLK, 0, stream>>>(
            user_emb, UU.rsq_out, embA, uu_sum);

        float* bufs[2] = {embA, embB};
        for (int l = 0; l < 2; ++l) {
            gcn_layer_kernel<<<cdiv(N_USER, BLK / 64), BLK, 0, stream>>>(
                UU.row_ptr, UU.col, bufs[l & 1], UU.rsq_in, UU.rsq_out,
                uu_sum, bufs[(l + 1) & 1], N_USER);
        }
    }
}

// Round 3
// 1378.861 us; speedup vs baseline: 2.5882x; 1.0621x over previous
//
#include <hip/hip_runtime.h>
#include <hip/hip_bf16.h>

constexpr int N_USER = 100000;
constexpr int N_ITEM = 200000;
constexpr int N_ALL  = N_USER + N_ITEM;
constexpr int E_UI   = 3200000;
constexpr int E_UU   = 1600000;
constexpr int D      = 64;
constexpr int BLK    = 256;

typedef __hip_bfloat16 bf16;

// ---------------- small helpers ----------------

__device__ inline int wave_incl_scan(int x, int lane) {
    #pragma unroll
    for (int off = 1; off < 64; off <<= 1) {
        int y = __shfl_up(x, off, 64);
        if (lane >= off) x += y;
    }
    return x;
}

// ---------------- init kernels ----------------

// emb_scaled(bf16) = concat(ue,ie) * rsq_out[row];  ui_sum(f32) = concat(ue,ie)
__global__ void init_ui_kernel(const float* __restrict__ ue,
                               const float* __restrict__ ie,
                               const float* __restrict__ rsq_out,
                               bf16* __restrict__ emb_scaled,
                               float* __restrict__ ui_sum) {
    size_t t = (size_t)blockIdx.x * blockDim.x + threadIdx.x;
    const size_t total = (size_t)N_ALL * D;
    if (t >= total) return;
    const size_t userN = (size_t)N_USER * D;
    float v = (t < userN) ? ue[t] : ie[t - userN];
    int row = (int)(t >> 6);
    emb_scaled[t] = __float2bfloat16(v * rsq_out[row]);
    ui_sum[t] = v;
}

__global__ void init_uu_kernel(const float* __restrict__ ue,
                               const float* __restrict__ rsq_out,
                               bf16* __restrict__ emb_scaled,
                               float* __restrict__ uu_sum) {
    size_t t = (size_t)blockIdx.x * blockDim.x + threadIdx.x;
    const size_t total = (size_t)N_USER * D;
    if (t >= total) return;
    float v = ue[t];
    int row = (int)(t >> 6);
    emb_scaled[t] = __float2bfloat16(v * rsq_out[row]);
    uu_sum[t] = v;
}

// ---------------- degree / CSR build ----------------

__global__ void hist_kernel(const int* __restrict__ src,
                            const int* __restrict__ dst, int E,
                            int* __restrict__ cnt_out,
                            int* __restrict__ cnt_in) {
    int e = blockIdx.x * blockDim.x + threadIdx.x;
    if (e >= E) return;
    atomicAdd(&cnt_out[src[e]], 1);
    atomicAdd(&cnt_in[dst[e]], 1);
}

__global__ void rsq_from_cnt_kernel(const int* __restrict__ co,
                                    const int* __restrict__ ci,
                                    float* __restrict__ ro,
                                    float* __restrict__ ri, int n) {
    int i = blockIdx.x * blockDim.x + threadIdx.x;
    if (i >= n) return;
    ro[i] = 1.0f / sqrtf(fmaxf((float)co[i], 1.0f));
    ri[i] = 1.0f / sqrtf(fmaxf((float)ci[i], 1.0f));
}

// exclusive scan of cnt[0..n) -> row_ptr[1..n] (local inclusive), blk_sums[b]=block total
__global__ void scan1_kernel(const int* __restrict__ cnt,
                             int* __restrict__ row_ptr,
                             int* __restrict__ blk_sums, int n) {
    int i = blockIdx.x * BLK + threadIdx.x;
    int lane = threadIdx.x & 63, wid = threadIdx.x >> 6;
    int x = (i < n) ? cnt[i] : 0;
    int s = wave_incl_scan(x, lane);
    __shared__ int wsum[4];
    if (lane == 63) wsum[wid] = s;
    __syncthreads();
    int add = 0;
    for (int w = 0; w < wid; ++w) add += wsum[w];
    s += add;
    if (i < n) row_ptr[i + 1] = s;
    if (threadIdx.x == BLK - 1) blk_sums[blockIdx.x] = s;
}

// in-place exclusive scan of blk_sums[0..nb), single block
__global__ void scan2_kernel(int* __restrict__ data, int nb) {
    __shared__ int wsum[4];
    __shared__ int carry_s;
    int lane = threadIdx.x & 63, wid = threadIdx.x >> 6;
    if (threadIdx.x == 0) carry_s = 0;
    for (int base = 0; base < nb; base += BLK) {
        __syncthreads();
        int i = base + threadIdx.x;
        int x = (i < nb) ? data[i] : 0;
        int s = wave_incl_scan(x, lane);
        if (lane == 63) wsum[wid] = s;
        __syncthreads();
        int add = carry_s;
        for (int w = 0; w < wid; ++w) add += wsum[w];
        int excl = add + s - x;
        if (i < nb) data[i] = excl;
        int total = wsum[0] + wsum[1] + wsum[2] + wsum[3];
        __syncthreads();
        if (threadIdx.x == 0) carry_s = add + total;  // add==old carry for t0
    }
}

__global__ void scan3_kernel(int* __restrict__ row_ptr,
                             const int* __restrict__ blk_offs, int n) {
    int i = blockIdx.x * BLK + threadIdx.x;
    if (i < n) row_ptr[i + 1] += blk_offs[blockIdx.x];
    if (i == 0) row_ptr[0] = 0;
}

__global__ void copy_int_kernel(const int* __restrict__ a, int* __restrict__ b, int n) {
    int i = blockIdx.x * blockDim.x + threadIdx.x;
    if (i < n) b[i] = a[i];
}

__global__ void build_csr_kernel(const int* __restrict__ src,
                                 const int* __restrict__ dst, int E,
                                 int* __restrict__ cursor,
                                 int* __restrict__ col) {
    int e = blockIdx.x * blockDim.x + threadIdx.x;
    if (e >= E) return;
    int pos = atomicAdd(&cursor[dst[e]], 1);
    col[pos] = src[e];
}

// ---------------- fused GCN layer (gather, no atomics, bf16 emb) ----------------
// One wave per destination row:
//   acc = sum_{s in N_in(row)} emb_in[s]          (emb_in pre-scaled by rsq_out)
//   v   = LeakyReLU_{0.5}(acc * rsq_in[row])
//   sum_out[row] += v / max(||v||, 1e-12)
//   emb_out[row]  = v * rsq_out[row]              (pre-scale for next layer)
__global__ void gcn_layer_kernel(const int* __restrict__ row_ptr,
                                 const int* __restrict__ col,
                                 const bf16* __restrict__ emb_in,
                                 const float* __restrict__ rsq_in,
                                 const float* __restrict__ rsq_out,
                                 float* __restrict__ sum_out,
                                 bf16* __restrict__ emb_out,
                                 int n) {
    int row = blockIdx.x * (blockDim.x >> 6) + (threadIdx.x >> 6);
    int lane = threadIdx.x & 63;
    if (row >= n) return;
    int beg = row_ptr[row], end = row_ptr[row + 1];
    float acc = 0.f;
    for (int c = beg; c < end; c += 64) {
        int m = min(64, end - c);
        int sidx = (c + lane < end) ? col[c + lane] : 0;
        int j = 0;
        for (; j + 4 <= m; j += 4) {
            int s0 = __shfl(sidx, j, 64);
            int s1 = __shfl(sidx, j + 1, 64);
            int s2 = __shfl(sidx, j + 2, 64);
            int s3 = __shfl(sidx, j + 3, 64);
            float a0 = __bfloat162float(emb_in[(size_t)s0 * D + lane]);
            float a1 = __bfloat162float(emb_in[(size_t)s1 * D + lane]);
            float a2 = __bfloat162float(emb_in[(size_t)s2 * D + lane]);
            float a3 = __bfloat162float(emb_in[(size_t)s3 * D + lane]);
            acc += a0; acc += a1; acc += a2; acc += a3;
        }
        for (; j < m; ++j) {
            int s = __shfl(sidx, j, 64);
            acc += __bfloat162float(emb_in[(size_t)s * D + lane]);
        }
    }
    float v = acc * rsq_in[row];
    v = (v > 0.f) ? v : 0.5f * v;  // LeakyReLU(0.5)
    float ss = v * v;
    #pragma unroll
    for (int mm = 32; mm >= 1; mm >>= 1) ss += __shfl_xor(ss, mm, 64);
    float denom = fmaxf(sqrtf(ss), 1e-12f);
    size_t o = (size_t)row * D + lane;
    sum_out[o] += v / denom;
    emb_out[o] = __float2bfloat16(v * rsq_out[row]);
}

// ---------------- host side ----------------

static inline int cdiv(int a, int b) { return (a + b - 1) / b; }

struct CsrBufs {
    int *cnt_out, *cnt_in, *row_ptr, *cursor, *col, *blk_sums;
    float *rsq_out, *rsq_in;
};

static void build_graph(const int* src, const int* dst, int E, int n,
                        CsrBufs& B, hipStream_t stream) {
    hipMemsetAsync(B.cnt_out, 0, (size_t)n * sizeof(int), stream);
    hipMemsetAsync(B.cnt_in,  0, (size_t)n * sizeof(int), stream);
    hist_kernel<<<cdiv(E, BLK), BLK, 0, stream>>>(src, dst, E, B.cnt_out, B.cnt_in);
    rsq_from_cnt_kernel<<<cdiv(n, BLK), BLK, 0, stream>>>(B.cnt_out, B.cnt_in,
                                                          B.rsq_out, B.rsq_in, n);
    int nb = cdiv(n, BLK);
    scan1_kernel<<<nb, BLK, 0, stream>>>(B.cnt_in, B.row_ptr, B.blk_sums, n);
    scan2_kernel<<<1, BLK, 0, stream>>>(B.blk_sums, nb);
    scan3_kernel<<<nb, BLK, 0, stream>>>(B.row_ptr, B.blk_sums, n);
    copy_int_kernel<<<cdiv(n, BLK), BLK, 0, stream>>>(B.row_ptr, B.cursor, n);
    build_csr_kernel<<<cdiv(E, BLK), BLK, 0, stream>>>(src, dst, E, B.cursor, B.col);
}

extern "C" void kernel_launch(void* const* d_in, const int* in_sizes, int n_in,
                              void* d_out, int out_size, void* d_ws, size_t ws_size,
                              hipStream_t stream) {
    const float* user_emb = (const float*)d_in[0];
    const float* item_emb = (const float*)d_in[1];
    const int*   ui_src   = (const int*)d_in[2];
    const int*   ui_dst   = (const int*)d_in[3];
    const int*   uu_src   = (const int*)d_in[4];
    const int*   uu_dst   = (const int*)d_in[5];

    float* out    = (float*)d_out;
    float* ui_sum = out;                          // [N_ALL * D]
    float* uu_sum = out + (size_t)N_ALL * D;      // [N_USER * D]

    // ws: two ping-pong bf16 emb buffers (pre-scaled by rsq_out), 38.4 MB each
    bf16* embA = (bf16*)d_ws;
    bf16* embB = embA + (size_t)N_ALL * D;

    // UI CSR scratch lives in the uu_sum region of d_out (dead during UI phase).
    // Budget 25.6 MB; we use ~20.0 MB.
    {
        char* p = (char*)uu_sum;
        CsrBufs UI;
        UI.col      = (int*)p;            p += (size_t)E_UI * sizeof(int);
        UI.row_ptr  = (int*)p;            p += (size_t)(N_ALL + 1) * sizeof(int);
        UI.cursor   = (int*)p;            p += (size_t)N_ALL * sizeof(int);
        UI.cnt_out  = (int*)p;            p += (size_t)N_ALL * sizeof(int);
        UI.cnt_in   = (int*)p;            p += (size_t)N_ALL * sizeof(int);
        UI.rsq_out  = (float*)p;          p += (size_t)N_ALL * sizeof(float);
        UI.rsq_in   = (float*)p;          p += (size_t)N_ALL * sizeof(float);
        UI.blk_sums = (int*)p;            p += 8192;

        build_graph(ui_src, ui_dst, E_UI, N_ALL, UI, stream);

        size_t tot = (size_t)N_ALL * D;
        init_ui_kernel<<<cdiv((int)tot, BLK), BLK, 0, stream>>>(
            user_emb, item_emb, UI.rsq_out, embA, ui_sum);

        bf16* bufs[2] = {embA, embB};
        for (int l = 0; l < 3; ++l) {
            gcn_layer_kernel<<<cdiv(N_ALL, BLK / 64), BLK, 0, stream>>>(
                UI.row_ptr, UI.col, bufs[l & 1], UI.rsq_in, UI.rsq_out,
                ui_sum, bufs[(l + 1) & 1], N_ALL);
        }
    }

    // UU CSR scratch lives in the upper (unused) part of embA: UU layers only
    // touch the first N_USER rows (12.8 MB) of each emb buffer. Budget 25.6 MB;
    // we use ~8.8 MB.
    {
        char* p = (char*)(embA + (size_t)N_USER * D);
        CsrBufs UU;
        UU.col      = (int*)p;            p += (size_t)E_UU * sizeof(int);
        UU.row_ptr  = (int*)p;            p += (size_t)(N_USER + 1) * sizeof(int);
        UU.cursor   = (int*)p;            p += (size_t)N_USER * sizeof(int);
        UU.cnt_out  = (int*)p;            p += (size_t)N_USER * sizeof(int);
        UU.cnt_in   = (int*)p;            p += (size_t)N_USER * sizeof(int);
        UU.rsq_out  = (float*)p;          p += (size_t)N_USER * sizeof(float);
        UU.rsq_in   = (float*)p;          p += (size_t)N_USER * sizeof(float);
        UU.blk_sums = (int*)p;            p += 8192;

        build_graph(uu_src, uu_dst, E_UU, N_USER, UU, stream);

        size_t tot = (size_t)N_USER * D;
        init_uu_kernel<<<cdiv((int)tot, BLK), BLK, 0, stream>>>(
            user_emb, UU.rsq_out, embA, uu_sum);

        bf16* bufs[2] = {embA, embB};
        for (int l = 0; l < 2; ++l) {
            gcn_layer_kernel<<<cdiv(N_USER, BLK / 64), BLK, 0, stream>>>(
                UU.row_ptr, UU.col, bufs[l & 1], UU.rsq_in, UU.rsq_out,
                uu_sum, bufs[(l + 1) & 1], N_USER);
        }
    }
}

// Round 4
// 959.459 us; speedup vs baseline: 3.7196x; 1.4371x over previous
//
#include <hip/hip_runtime.h>
#include <hip/hip_bf16.h>

constexpr int N_USER = 100000;
constexpr int N_ITEM = 200000;
constexpr int N_ALL  = N_USER + N_ITEM;
constexpr int E_UI   = 3200000;
constexpr int E_UU   = 1600000;
constexpr int D      = 64;
constexpr int BLK    = 256;

// bucketing: 512 destination rows per bucket
constexpr int RPB_SHIFT = 9;
constexpr int RPB       = 1 << RPB_SHIFT;   // 512
constexpr int MAX_NB    = 1024;             // >= cdiv(N_ALL, RPB) = 586

// bin_scatter tile geometry
constexpr int SBLK = 512;
constexpr int EPT  = 16;
constexpr int TILE = SBLK * EPT;            // 8192 edges per block

typedef __hip_bfloat16 bf16;

// ---------------- small helpers ----------------

__device__ inline int wave_incl_scan(int x, int lane) {
    #pragma unroll
    for (int off = 1; off < 64; off <<= 1) {
        int y = __shfl_up(x, off, 64);
        if (lane >= off) x += y;
    }
    return x;
}

static inline int cdiv(int a, int b) { return (a + b - 1) / b; }

// ---------------- init kernels ----------------

__global__ void init_ui_kernel(const float* __restrict__ ue,
                               const float* __restrict__ ie,
                               const float* __restrict__ rsq_out,
                               bf16* __restrict__ emb_scaled,
                               float* __restrict__ ui_sum) {
    size_t t = (size_t)blockIdx.x * blockDim.x + threadIdx.x;
    const size_t total = (size_t)N_ALL * D;
    if (t >= total) return;
    const size_t userN = (size_t)N_USER * D;
    float v = (t < userN) ? ue[t] : ie[t - userN];
    int row = (int)(t >> 6);
    emb_scaled[t] = __float2bfloat16(v * rsq_out[row]);
    ui_sum[t] = v;
}

__global__ void init_uu_kernel(const float* __restrict__ ue,
                               const float* __restrict__ rsq_out,
                               bf16* __restrict__ emb_scaled,
                               float* __restrict__ uu_sum) {
    size_t t = (size_t)blockIdx.x * blockDim.x + threadIdx.x;
    const size_t total = (size_t)N_USER * D;
    if (t >= total) return;
    float v = ue[t];
    int row = (int)(t >> 6);
    emb_scaled[t] = __float2bfloat16(v * rsq_out[row]);
    uu_sum[t] = v;
}

// ---------------- out-degree (random atomics, small table) ----------------

__global__ void hist_src_kernel(const int* __restrict__ src, int E,
                                int* __restrict__ cnt) {
    int e = blockIdx.x * blockDim.x + threadIdx.x;
    if (e < E) atomicAdd(&cnt[src[e]], 1);
}

__global__ void rsq_out_kernel(const int* __restrict__ cnt,
                               float* __restrict__ ro, int n) {
    int i = blockIdx.x * blockDim.x + threadIdx.x;
    if (i < n) ro[i] = 1.0f / sqrtf(fmaxf((float)cnt[i], 1.0f));
}

// ---------------- bucket histogram (LDS-aggregated) ----------------

__global__ void bucket_hist_kernel(const int* __restrict__ dst, int E, int nb,
                                   int* __restrict__ bcnt_g) {
    __shared__ int c[MAX_NB];
    for (int b = threadIdx.x; b < nb; b += blockDim.x) c[b] = 0;
    __syncthreads();
    for (int e = blockIdx.x * blockDim.x + threadIdx.x; e < E;
         e += gridDim.x * blockDim.x)
        atomicAdd(&c[dst[e] >> RPB_SHIFT], 1);
    __syncthreads();
    for (int b = threadIdx.x; b < nb; b += blockDim.x)
        if (c[b]) atomicAdd(&bcnt_g[b], c[b]);
}

// single-block exclusive scan of bucket counts -> base[0..nb] (sentinel=E), cursor copy
__global__ void scan_buckets_kernel(const int* __restrict__ cnt, int nb,
                                    int* __restrict__ base,
                                    int* __restrict__ cursor) {
    __shared__ int wsum[4];
    __shared__ int carry_s;
    int t = threadIdx.x, lane = t & 63, wid = t >> 6;
    if (t == 0) carry_s = 0;
    for (int b0 = 0; b0 < nb; b0 += BLK) {
        __syncthreads();
        int i = b0 + t;
        int x = (i < nb) ? cnt[i] : 0;
        int s = wave_incl_scan(x, lane);
        if (lane == 63) wsum[wid] = s;
        __syncthreads();
        int add = carry_s;
        for (int w = 0; w < wid; ++w) add += wsum[w];
        int excl = add + s - x;
        if (i < nb) { base[i] = excl; cursor[i] = excl; }
        int total = wsum[0] + wsum[1] + wsum[2] + wsum[3];
        __syncthreads();
        if (t == 0) carry_s = add + total;  // add == old carry for t0
    }
    __syncthreads();
    if (t == 0) base[nb] = carry_s;
}

// ---------------- bin scatter: edges -> bucket-contiguous (dst,src) pairs ----------------

__global__ __launch_bounds__(SBLK) void bin_scatter_kernel(
    const int* __restrict__ src, const int* __restrict__ dst, int E, int nb,
    int* __restrict__ cursor, int2* __restrict__ binned) {
    __shared__ int bcnt[MAX_NB];
    __shared__ int bbase[MAX_NB];
    int t = threadIdx.x;
    for (int b = t; b < nb; b += SBLK) bcnt[b] = 0;
    __syncthreads();
    int base_e = blockIdx.x * TILE;
    int myd[EPT], mys[EPT], myr[EPT];
    #pragma unroll
    for (int j = 0; j < EPT; ++j) {
        int e = base_e + j * SBLK + t;
        if (e < E) {
            int d = dst[e];
            mys[j] = src[e];
            myd[j] = d;
            myr[j] = atomicAdd(&bcnt[d >> RPB_SHIFT], 1);
        } else {
            myd[j] = -1;
        }
    }
    __syncthreads();
    for (int b = t; b < nb; b += SBLK)
        if (bcnt[b] > 0) bbase[b] = atomicAdd(&cursor[b], bcnt[b]);
    __syncthreads();
    #pragma unroll
    for (int j = 0; j < EPT; ++j) {
        if (myd[j] >= 0) {
            int b = myd[j] >> RPB_SHIFT;
            binned[bbase[b] + myr[j]] = make_int2(myd[j], mys[j]);
        }
    }
}

// ---------------- per-bucket CSR finalize ----------------
// One block per bucket: per-row degree count (LDS), LDS scan -> row_ptr/rsq_in,
// then scatter col[] into the bucket's contiguous region.
__global__ void bucket_csr_kernel(const int2* __restrict__ binned,
                                  const int* __restrict__ base, int nb, int n,
                                  int* __restrict__ row_ptr,
                                  float* __restrict__ rsq_in,
                                  int* __restrict__ col) {
    __shared__ int deg[RPB];
    __shared__ int cur[RPB];
    __shared__ int wsum[4];
    __shared__ int tot0_s;
    int b = blockIdx.x;
    int row0 = b << RPB_SHIFT;
    int nrows = min(RPB, n - row0);
    int t = threadIdx.x, lane = t & 63, wid = t >> 6;
    int beg = base[b], end = base[b + 1];

    deg[t] = 0;
    deg[t + BLK] = 0;
    __syncthreads();

    for (int e = beg + t; e < end; e += BLK)
        atomicAdd(&deg[binned[e].x - row0], 1);
    __syncthreads();

    // exclusive scan of deg[0..512) with 256 threads, two passes
    int x0 = deg[t];
    int s0 = wave_incl_scan(x0, lane);
    if (lane == 63) wsum[wid] = s0;
    __syncthreads();
    int add0 = 0;
    for (int w = 0; w < wid; ++w) add0 += wsum[w];
    int incl0 = s0 + add0;
    int tot0 = wsum[0] + wsum[1] + wsum[2] + wsum[3];
    __syncthreads();  // protect wsum before pass 2

    int x1 = deg[t + BLK];
    int s1 = wave_incl_scan(x1, lane);
    if (lane == 63) wsum[wid] = s1;
    __syncthreads();
    int add1 = 0;
    for (int w = 0; w < wid; ++w) add1 += wsum[w];
    int incl1 = s1 + add1;

    int excl0 = incl0 - x0;
    int excl1 = tot0 + incl1 - x1;
    cur[t] = beg + excl0;
    cur[t + BLK] = beg + excl1;
    if (t < nrows) {
        row_ptr[row0 + t] = beg + excl0;
        rsq_in[row0 + t] = 1.0f / sqrtf(fmaxf((float)x0, 1.0f));
    }
    if (t + BLK < nrows) {
        row_ptr[row0 + t + BLK] = beg + excl1;
        rsq_in[row0 + t + BLK] = 1.0f / sqrtf(fmaxf((float)x1, 1.0f));
    }
    if (b == nb - 1 && t == 0) row_ptr[n] = end;
    __syncthreads();

    for (int e = beg + t; e < end; e += BLK) {
        int2 p = binned[e];
        int pos = atomicAdd(&cur[p.x - row0], 1);
        col[pos] = p.y;
    }
}

// ---------------- fused GCN layer (gather, no atomics, bf16 emb) ----------------

__global__ void gcn_layer_kernel(const int* __restrict__ row_ptr,
                                 const int* __restrict__ col,
                                 const bf16* __restrict__ emb_in,
                                 const float* __restrict__ rsq_in,
                                 const float* __restrict__ rsq_out,
                                 float* __restrict__ sum_out,
                                 bf16* __restrict__ emb_out,
                                 int n) {
    int row = blockIdx.x * (blockDim.x >> 6) + (threadIdx.x >> 6);
    int lane = threadIdx.x & 63;
    if (row >= n) return;
    int beg = row_ptr[row], end = row_ptr[row + 1];
    float acc = 0.f;
    for (int c = beg; c < end; c += 64) {
        int m = min(64, end - c);
        int sidx = (c + lane < end) ? col[c + lane] : 0;
        int j = 0;
        for (; j + 4 <= m; j += 4) {
            int s0 = __shfl(sidx, j, 64);
            int s1 = __shfl(sidx, j + 1, 64);
            int s2 = __shfl(sidx, j + 2, 64);
            int s3 = __shfl(sidx, j + 3, 64);
            float a0 = __bfloat162float(emb_in[(size_t)s0 * D + lane]);
            float a1 = __bfloat162float(emb_in[(size_t)s1 * D + lane]);
            float a2 = __bfloat162float(emb_in[(size_t)s2 * D + lane]);
            float a3 = __bfloat162float(emb_in[(size_t)s3 * D + lane]);
            acc += a0; acc += a1; acc += a2; acc += a3;
        }
        for (; j < m; ++j) {
            int s = __shfl(sidx, j, 64);
            acc += __bfloat162float(emb_in[(size_t)s * D + lane]);
        }
    }
    float v = acc * rsq_in[row];
    v = (v > 0.f) ? v : 0.5f * v;  // LeakyReLU(0.5)
    float ss = v * v;
    #pragma unroll
    for (int mm = 32; mm >= 1; mm >>= 1) ss += __shfl_xor(ss, mm, 64);
    float denom = fmaxf(sqrtf(ss), 1e-12f);
    size_t o = (size_t)row * D + lane;
    sum_out[o] += v / denom;
    emb_out[o] = __float2bfloat16(v * rsq_out[row]);
}

// ---------------- host side ----------------

struct GraphBufs {
    int *col, *row_ptr, *cnt_out;
    float *rsq_out, *rsq_in;
    int *bucket_cnt, *bucket_base, *bucket_cursor;
    int2 *binned;
};

static void build_graph(const int* src, const int* dst, int E, int n, int nb,
                        GraphBufs& B, hipStream_t stream) {
    hipMemsetAsync(B.cnt_out, 0, (size_t)n * sizeof(int), stream);
    hipMemsetAsync(B.bucket_cnt, 0, (size_t)nb * sizeof(int), stream);
    hist_src_kernel<<<cdiv(E, BLK), BLK, 0, stream>>>(src, E, B.cnt_out);
    bucket_hist_kernel<<<512, BLK, 0, stream>>>(dst, E, nb, B.bucket_cnt);
    rsq_out_kernel<<<cdiv(n, BLK), BLK, 0, stream>>>(B.cnt_out, B.rsq_out, n);
    scan_buckets_kernel<<<1, BLK, 0, stream>>>(B.bucket_cnt, nb, B.bucket_base,
                                               B.bucket_cursor);
    bin_scatter_kernel<<<cdiv(E, TILE), SBLK, 0, stream>>>(src, dst, E, nb,
                                                           B.bucket_cursor, B.binned);
    bucket_csr_kernel<<<nb, BLK, 0, stream>>>(B.binned, B.bucket_base, nb, n,
                                              B.row_ptr, B.rsq_in, B.col);
}

extern "C" void kernel_launch(void* const* d_in, const int* in_sizes, int n_in,
                              void* d_out, int out_size, void* d_ws, size_t ws_size,
                              hipStream_t stream) {
    const float* user_emb = (const float*)d_in[0];
    const float* item_emb = (const float*)d_in[1];
    const int*   ui_src   = (const int*)d_in[2];
    const int*   ui_dst   = (const int*)d_in[3];
    const int*   uu_src   = (const int*)d_in[4];
    const int*   uu_dst   = (const int*)d_in[5];

    float* out    = (float*)d_out;
    float* ui_sum = out;                          // [N_ALL * D]
    float* uu_sum = out + (size_t)N_ALL * D;      // [N_USER * D]

    const int NB_UI = cdiv(N_ALL, RPB);   // 586
    const int NB_UU = cdiv(N_USER, RPB);  // 196

    // ws layout: embA | embB | binned (E_UI) | UU scratch | bucket arrays
    char* wp = (char*)d_ws;
    bf16* embA = (bf16*)wp;  wp += (size_t)N_ALL * D * sizeof(bf16);   // 38.4 MB
    bf16* embB = (bf16*)wp;  wp += (size_t)N_ALL * D * sizeof(bf16);   // 38.4 MB
    int2* binned = (int2*)wp; wp += (size_t)E_UI * sizeof(int2);       // 25.6 MB
    // UU scratch (used only in UU phase)
    int*   uu_col     = (int*)wp;   wp += (size_t)E_UU * sizeof(int);        // 6.4 MB
    int*   uu_row_ptr = (int*)wp;   wp += (size_t)(N_USER + 1) * sizeof(int);
    int*   uu_cnt_out = (int*)wp;   wp += (size_t)N_USER * sizeof(int);
    float* uu_rsq_out = (float*)wp; wp += (size_t)N_USER * sizeof(float);
    float* uu_rsq_in  = (float*)wp; wp += (size_t)N_USER * sizeof(float);
    // shared small bucket arrays
    int* bucket_cnt    = (int*)wp;  wp += (size_t)MAX_NB * sizeof(int);
    int* bucket_base   = (int*)wp;  wp += (size_t)(MAX_NB + 1) * sizeof(int);
    int* bucket_cursor = (int*)wp;  wp += (size_t)MAX_NB * sizeof(int);

    // ---------------- user-item graph ----------------
    {
        // UI CSR scratch lives in the uu_sum region of d_out (dead during UI phase).
        // Budget 25.6 MB; we use ~17.6 MB.
        char* p = (char*)uu_sum;
        GraphBufs UI;
        UI.col      = (int*)p;   p += (size_t)E_UI * sizeof(int);          // 12.8 MB
        UI.row_ptr  = (int*)p;   p += (size_t)(N_ALL + 1) * sizeof(int);   // 1.2 MB
        UI.cnt_out  = (int*)p;   p += (size_t)N_ALL * sizeof(int);         // 1.2 MB
        UI.rsq_out  = (float*)p; p += (size_t)N_ALL * sizeof(float);       // 1.2 MB
        UI.rsq_in   = (float*)p; p += (size_t)N_ALL * sizeof(float);       // 1.2 MB
        UI.bucket_cnt = bucket_cnt;
        UI.bucket_base = bucket_base;
        UI.bucket_cursor = bucket_cursor;
        UI.binned = binned;

        build_graph(ui_src, ui_dst, E_UI, N_ALL, NB_UI, UI, stream);

        size_t tot = (size_t)N_ALL * D;
        init_ui_kernel<<<cdiv((int)tot, BLK), BLK, 0, stream>>>(
            user_emb, item_emb, UI.rsq_out, embA, ui_sum);

        bf16* bufs[2] = {embA, embB};
        for (int l = 0; l < 3; ++l) {
            gcn_layer_kernel<<<cdiv(N_ALL, BLK / 64), BLK, 0, stream>>>(
                UI.row_ptr, UI.col, bufs[l & 1], UI.rsq_in, UI.rsq_out,
                ui_sum, bufs[(l + 1) & 1], N_ALL);
        }
    }

    // ---------------- user-user graph ----------------
    {
        GraphBufs UU;
        UU.col = uu_col;
        UU.row_ptr = uu_row_ptr;
        UU.cnt_out = uu_cnt_out;
        UU.rsq_out = uu_rsq_out;
        UU.rsq_in = uu_rsq_in;
        UU.bucket_cnt = bucket_cnt;
        UU.bucket_base = bucket_base;
        UU.bucket_cursor = bucket_cursor;
        UU.binned = binned;   // reuse (only first E_UU entries)

        build_graph(uu_src, uu_dst, E_UU, N_USER, NB_UU, UU, stream);

        size_t tot = (size_t)N_USER * D;
        init_uu_kernel<<<cdiv((int)tot, BLK), BLK, 0, stream>>>(
            user_emb, UU.rsq_out, embA, uu_sum);

        bf16* bufs[2] = {embA, embB};
        for (int l = 0; l < 2; ++l) {
            gcn_layer_kernel<<<cdiv(N_USER, BLK / 64), BLK, 0, stream>>>(
                UU.row_ptr, UU.col, bufs[l & 1], UU.rsq_in, UU.rsq_out,
                uu_sum, bufs[(l + 1) & 1], N_USER);
        }
    }
}

// Round 5
// 787.273 us; speedup vs baseline: 4.5331x; 1.2187x over previous
//
#include <hip/hip_runtime.h>
#include <hip/hip_bf16.h>

constexpr int N_USER = 100000;
constexpr int N_ITEM = 200000;
constexpr int N_ALL  = N_USER + N_ITEM;
constexpr int E_UI   = 3200000;
constexpr int E_UU   = 1600000;
constexpr int D      = 64;
constexpr int BLK    = 256;

// bucketing: 512 destination rows per bucket
constexpr int RPB_SHIFT = 9;
constexpr int RPB       = 1 << RPB_SHIFT;   // 512
constexpr int MAX_NB    = 1024;             // >= cdiv(N_ALL, RPB) = 586

// bin_scatter tile geometry
constexpr int SBLK = 512;
constexpr int EPT  = 16;
constexpr int TILE = SBLK * EPT;            // 8192 edges per block

typedef __hip_bfloat16 bf16;

// ---------------- small helpers ----------------

__device__ inline int wave_incl_scan(int x, int lane) {
    #pragma unroll
    for (int off = 1; off < 64; off <<= 1) {
        int y = __shfl_up(x, off, 64);
        if (lane >= off) x += y;
    }
    return x;
}

static inline int cdiv(int a, int b) { return (a + b - 1) / b; }

// ---------------- init kernels (scaled bf16 emb only; sums fused into layer 1) ----------------

__global__ void init_ui_kernel(const float* __restrict__ ue,
                               const float* __restrict__ ie,
                               const float* __restrict__ rsq_out,
                               bf16* __restrict__ emb_scaled) {
    size_t t = (size_t)blockIdx.x * blockDim.x + threadIdx.x;
    const size_t total = (size_t)N_ALL * D;
    if (t >= total) return;
    const size_t userN = (size_t)N_USER * D;
    float v = (t < userN) ? ue[t] : ie[t - userN];
    int row = (int)(t >> 6);
    emb_scaled[t] = __float2bfloat16(v * rsq_out[row]);
}

__global__ void init_uu_kernel(const float* __restrict__ ue,
                               const float* __restrict__ rsq_out,
                               bf16* __restrict__ emb_scaled) {
    size_t t = (size_t)blockIdx.x * blockDim.x + threadIdx.x;
    const size_t total = (size_t)N_USER * D;
    if (t >= total) return;
    float v = ue[t];
    int row = (int)(t >> 6);
    emb_scaled[t] = __float2bfloat16(v * rsq_out[row]);
}

// ---------------- out-degree (random atomics, small table) ----------------

__global__ void hist_src_kernel(const int* __restrict__ src, int E,
                                int* __restrict__ cnt) {
    int e = blockIdx.x * blockDim.x + threadIdx.x;
    if (e < E) atomicAdd(&cnt[src[e]], 1);
}

__global__ void rsq_out_kernel(const int* __restrict__ cnt,
                               float* __restrict__ ro, int n) {
    int i = blockIdx.x * blockDim.x + threadIdx.x;
    if (i < n) ro[i] = 1.0f / sqrtf(fmaxf((float)cnt[i], 1.0f));
}

// ---------------- bucket histogram (LDS-aggregated) ----------------

__global__ void bucket_hist_kernel(const int* __restrict__ dst, int E, int nb,
                                   int* __restrict__ bcnt_g) {
    __shared__ int c[MAX_NB];
    for (int b = threadIdx.x; b < nb; b += blockDim.x) c[b] = 0;
    __syncthreads();
    for (int e = blockIdx.x * blockDim.x + threadIdx.x; e < E;
         e += gridDim.x * blockDim.x)
        atomicAdd(&c[dst[e] >> RPB_SHIFT], 1);
    __syncthreads();
    for (int b = threadIdx.x; b < nb; b += blockDim.x)
        if (c[b]) atomicAdd(&bcnt_g[b], c[b]);
}

// single-block exclusive scan of bucket counts -> base[0..nb] (sentinel=E), cursor copy
__global__ void scan_buckets_kernel(const int* __restrict__ cnt, int nb,
                                    int* __restrict__ base,
                                    int* __restrict__ cursor) {
    __shared__ int wsum[4];
    __shared__ int carry_s;
    int t = threadIdx.x, lane = t & 63, wid = t >> 6;
    if (t == 0) carry_s = 0;
    for (int b0 = 0; b0 < nb; b0 += BLK) {
        __syncthreads();
        int i = b0 + t;
        int x = (i < nb) ? cnt[i] : 0;
        int s = wave_incl_scan(x, lane);
        if (lane == 63) wsum[wid] = s;
        __syncthreads();
        int add = carry_s;
        for (int w = 0; w < wid; ++w) add += wsum[w];
        int excl = add + s - x;
        if (i < nb) { base[i] = excl; cursor[i] = excl; }
        int total = wsum[0] + wsum[1] + wsum[2] + wsum[3];
        __syncthreads();
        if (t == 0) carry_s = add + total;  // add == old carry for t0
    }
    __syncthreads();
    if (t == 0) base[nb] = carry_s;
}

// ---------------- bin scatter: edges -> bucket-contiguous (dst,src) pairs ----------------

__global__ __launch_bounds__(SBLK) void bin_scatter_kernel(
    const int* __restrict__ src, const int* __restrict__ dst, int E, int nb,
    int* __restrict__ cursor, int2* __restrict__ binned) {
    __shared__ int bcnt[MAX_NB];
    __shared__ int bbase[MAX_NB];
    int t = threadIdx.x;
    for (int b = t; b < nb; b += SBLK) bcnt[b] = 0;
    __syncthreads();
    int base_e = blockIdx.x * TILE;
    int myd[EPT], mys[EPT], myr[EPT];
    #pragma unroll
    for (int j = 0; j < EPT; ++j) {
        int e = base_e + j * SBLK + t;
        if (e < E) {
            int d = dst[e];
            mys[j] = src[e];
            myd[j] = d;
            myr[j] = atomicAdd(&bcnt[d >> RPB_SHIFT], 1);
        } else {
            myd[j] = -1;
        }
    }
    __syncthreads();
    for (int b = t; b < nb; b += SBLK)
        if (bcnt[b] > 0) bbase[b] = atomicAdd(&cursor[b], bcnt[b]);
    __syncthreads();
    #pragma unroll
    for (int j = 0; j < EPT; ++j) {
        if (myd[j] >= 0) {
            int b = myd[j] >> RPB_SHIFT;
            binned[bbase[b] + myr[j]] = make_int2(myd[j], mys[j]);
        }
    }
}

// ---------------- per-bucket CSR finalize ----------------

__global__ void bucket_csr_kernel(const int2* __restrict__ binned,
                                  const int* __restrict__ base, int nb, int n,
                                  int* __restrict__ row_ptr,
                                  float* __restrict__ rsq_in,
                                  int* __restrict__ col) {
    __shared__ int deg[RPB];
    __shared__ int cur[RPB];
    __shared__ int wsum[4];
    int b = blockIdx.x;
    int row0 = b << RPB_SHIFT;
    int nrows = min(RPB, n - row0);
    int t = threadIdx.x, lane = t & 63, wid = t >> 6;
    int beg = base[b], end = base[b + 1];

    deg[t] = 0;
    deg[t + BLK] = 0;
    __syncthreads();

    for (int e = beg + t; e < end; e += BLK)
        atomicAdd(&deg[binned[e].x - row0], 1);
    __syncthreads();

    // exclusive scan of deg[0..512) with 256 threads, two passes
    int x0 = deg[t];
    int s0 = wave_incl_scan(x0, lane);
    if (lane == 63) wsum[wid] = s0;
    __syncthreads();
    int add0 = 0;
    for (int w = 0; w < wid; ++w) add0 += wsum[w];
    int incl0 = s0 + add0;
    int tot0 = wsum[0] + wsum[1] + wsum[2] + wsum[3];
    __syncthreads();  // protect wsum before pass 2

    int x1 = deg[t + BLK];
    int s1 = wave_incl_scan(x1, lane);
    if (lane == 63) wsum[wid] = s1;
    __syncthreads();
    int add1 = 0;
    for (int w = 0; w < wid; ++w) add1 += wsum[w];
    int incl1 = s1 + add1;

    int excl0 = incl0 - x0;
    int excl1 = tot0 + incl1 - x1;
    cur[t] = beg + excl0;
    cur[t + BLK] = beg + excl1;
    if (t < nrows) {
        row_ptr[row0 + t] = beg + excl0;
        rsq_in[row0 + t] = 1.0f / sqrtf(fmaxf((float)x0, 1.0f));
    }
    if (t + BLK < nrows) {
        row_ptr[row0 + t + BLK] = beg + excl1;
        rsq_in[row0 + t + BLK] = 1.0f / sqrtf(fmaxf((float)x1, 1.0f));
    }
    if (b == nb - 1 && t == 0) row_ptr[n] = end;
    __syncthreads();

    for (int e = beg + t; e < end; e += BLK) {
        int2 p = binned[e];
        int pos = atomicAdd(&cur[p.x - row0], 1);
        col[pos] = p.y;
    }
}

// ---------------- fused GCN layer: 8 rows/wave, 8 lanes/row ----------------
// Lane l: row slot r=l>>3, dim chunk q=l&7 (dims q*8..q*8+7).
// Per neighbor: the 8 lanes of a row slot fetch the full 128B bf16 row as int4
// each; unpack (bf16->f32 = <<16) and accumulate into 8 f32 regs. No shuffles
// in the inner loop. Epilogue: rsq_in scale, LeakyReLU, L2-norm (3 shfl_xor
// within the 8-lane group), sum_out = base + v/||v||, emb_out = bf16(v*rsq_out).
// baseA!=null => base read from baseA/baseB split at splitElems (layer 1);
// else base = sum_out (RMW).
__global__ void gcn_layer_kernel(const int* __restrict__ row_ptr,
                                 const int* __restrict__ col,
                                 const bf16* __restrict__ emb_in,
                                 const float* __restrict__ rsq_in,
                                 const float* __restrict__ rsq_out,
                                 const float* __restrict__ baseA,
                                 const float* __restrict__ baseB,
                                 long splitElems,
                                 float* __restrict__ sum_out,
                                 bf16* __restrict__ emb_out,
                                 int n) {
    int wave = blockIdx.x * (blockDim.x >> 6) + (threadIdx.x >> 6);
    int lane = threadIdx.x & 63;
    int q = lane & 7;                 // dim chunk
    int row = wave * 8 + (lane >> 3); // row slot
    bool act = row < n;
    int beg = 0, end = 0;
    if (act) { beg = row_ptr[row]; end = row_ptr[row + 1]; }

    float acc[8];
    #pragma unroll
    for (int k = 0; k < 8; ++k) acc[k] = 0.f;

    const int4* __restrict__ embv = (const int4*)emb_in;  // row s, chunk q at s*8+q

    int e = beg;
    for (; e + 2 <= end; e += 2) {
        int s0 = col[e];
        int s1 = col[e + 1];
        int4 w0 = embv[(size_t)s0 * 8 + q];
        int4 w1 = embv[(size_t)s1 * 8 + q];
        acc[0] += __int_as_float(w0.x << 16);
        acc[1] += __int_as_float(w0.x & 0xffff0000);
        acc[2] += __int_as_float(w0.y << 16);
        acc[3] += __int_as_float(w0.y & 0xffff0000);
        acc[4] += __int_as_float(w0.z << 16);
        acc[5] += __int_as_float(w0.z & 0xffff0000);
        acc[6] += __int_as_float(w0.w << 16);
        acc[7] += __int_as_float(w0.w & 0xffff0000);
        acc[0] += __int_as_float(w1.x << 16);
        acc[1] += __int_as_float(w1.x & 0xffff0000);
        acc[2] += __int_as_float(w1.y << 16);
        acc[3] += __int_as_float(w1.y & 0xffff0000);
        acc[4] += __int_as_float(w1.z << 16);
        acc[5] += __int_as_float(w1.z & 0xffff0000);
        acc[6] += __int_as_float(w1.w << 16);
        acc[7] += __int_as_float(w1.w & 0xffff0000);
    }
    if (e < end) {
        int s0 = col[e];
        int4 w0 = embv[(size_t)s0 * 8 + q];
        acc[0] += __int_as_float(w0.x << 16);
        acc[1] += __int_as_float(w0.x & 0xffff0000);
        acc[2] += __int_as_float(w0.y << 16);
        acc[3] += __int_as_float(w0.y & 0xffff0000);
        acc[4] += __int_as_float(w0.z << 16);
        acc[5] += __int_as_float(w0.z & 0xffff0000);
        acc[6] += __int_as_float(w0.w << 16);
        acc[7] += __int_as_float(w0.w & 0xffff0000);
    }

    float rin = act ? rsq_in[row] : 0.f;
    float vv[8];
    float ss = 0.f;
    #pragma unroll
    for (int k = 0; k < 8; ++k) {
        float v = acc[k] * rin;
        v = (v > 0.f) ? v : 0.5f * v;   // LeakyReLU(0.5)
        vv[k] = v;
        ss += v * v;
    }
    // L2-norm reduce across the 8 lanes of this row (xor within the group)
    ss += __shfl_xor(ss, 1, 64);
    ss += __shfl_xor(ss, 2, 64);
    ss += __shfl_xor(ss, 4, 64);
    float inv = 1.0f / fmaxf(sqrtf(ss), 1e-12f);

    if (act) {
        size_t o = (size_t)row * D + (size_t)q * 8;
        float base[8];
        if (baseA) {
            #pragma unroll
            for (int k = 0; k < 8; ++k) {
                size_t oo = o + k;
                base[k] = (oo < (size_t)splitElems) ? baseA[oo]
                                                    : baseB[oo - splitElems];
            }
        } else {
            const float4* sp = (const float4*)(sum_out + o);
            float4 b0 = sp[0], b1 = sp[1];
            base[0] = b0.x; base[1] = b0.y; base[2] = b0.z; base[3] = b0.w;
            base[4] = b1.x; base[5] = b1.y; base[6] = b1.z; base[7] = b1.w;
        }
        float4 o0, o1;
        o0.x = base[0] + vv[0] * inv;
        o0.y = base[1] + vv[1] * inv;
        o0.z = base[2] + vv[2] * inv;
        o0.w = base[3] + vv[3] * inv;
        o1.x = base[4] + vv[4] * inv;
        o1.y = base[5] + vv[5] * inv;
        o1.z = base[6] + vv[6] * inv;
        o1.w = base[7] + vv[7] * inv;
        float4* op = (float4*)(sum_out + o);
        op[0] = o0;
        op[1] = o1;

        float ro = rsq_out[row];
        union { int4 i4; bf16 h[8]; } pk;
        #pragma unroll
        for (int k = 0; k < 8; ++k) pk.h[k] = __float2bfloat16(vv[k] * ro);
        *(int4*)(emb_out + o) = pk.i4;
    }
}

// ---------------- host side ----------------

struct GraphBufs {
    int *col, *row_ptr, *cnt_out;
    float *rsq_out, *rsq_in;
    int *bucket_cnt, *bucket_base, *bucket_cursor;
    int2 *binned;
};

static void build_graph(const int* src, const int* dst, int E, int n, int nb,
                        GraphBufs& B, hipStream_t stream) {
    hipMemsetAsync(B.cnt_out, 0, (size_t)n * sizeof(int), stream);
    hipMemsetAsync(B.bucket_cnt, 0, (size_t)nb * sizeof(int), stream);
    hist_src_kernel<<<cdiv(E, BLK), BLK, 0, stream>>>(src, E, B.cnt_out);
    bucket_hist_kernel<<<512, BLK, 0, stream>>>(dst, E, nb, B.bucket_cnt);
    rsq_out_kernel<<<cdiv(n, BLK), BLK, 0, stream>>>(B.cnt_out, B.rsq_out, n);
    scan_buckets_kernel<<<1, BLK, 0, stream>>>(B.bucket_cnt, nb, B.bucket_base,
                                               B.bucket_cursor);
    bin_scatter_kernel<<<cdiv(E, TILE), SBLK, 0, stream>>>(src, dst, E, nb,
                                                           B.bucket_cursor, B.binned);
    bucket_csr_kernel<<<nb, BLK, 0, stream>>>(B.binned, B.bucket_base, nb, n,
                                              B.row_ptr, B.rsq_in, B.col);
}

extern "C" void kernel_launch(void* const* d_in, const int* in_sizes, int n_in,
                              void* d_out, int out_size, void* d_ws, size_t ws_size,
                              hipStream_t stream) {
    const float* user_emb = (const float*)d_in[0];
    const float* item_emb = (const float*)d_in[1];
    const int*   ui_src   = (const int*)d_in[2];
    const int*   ui_dst   = (const int*)d_in[3];
    const int*   uu_src   = (const int*)d_in[4];
    const int*   uu_dst   = (const int*)d_in[5];

    float* out    = (float*)d_out;
    float* ui_sum = out;                          // [N_ALL * D]
    float* uu_sum = out + (size_t)N_ALL * D;      // [N_USER * D]

    const int NB_UI = cdiv(N_ALL, RPB);   // 586
    const int NB_UU = cdiv(N_USER, RPB);  // 196

    // ws layout: embA | embB | binned (E_UI) | UU scratch | bucket arrays
    char* wp = (char*)d_ws;
    bf16* embA = (bf16*)wp;  wp += (size_t)N_ALL * D * sizeof(bf16);   // 38.4 MB
    bf16* embB = (bf16*)wp;  wp += (size_t)N_ALL * D * sizeof(bf16);   // 38.4 MB
    int2* binned = (int2*)wp; wp += (size_t)E_UI * sizeof(int2);       // 25.6 MB
    // UU scratch (used only in UU phase)
    int*   uu_col     = (int*)wp;   wp += (size_t)E_UU * sizeof(int);        // 6.4 MB
    int*   uu_row_ptr = (int*)wp;   wp += (size_t)(N_USER + 1) * sizeof(int);
    int*   uu_cnt_out = (int*)wp;   wp += (size_t)N_USER * sizeof(int);
    float* uu_rsq_out = (float*)wp; wp += (size_t)N_USER * sizeof(float);
    float* uu_rsq_in  = (float*)wp; wp += (size_t)N_USER * sizeof(float);
    // shared small bucket arrays
    int* bucket_cnt    = (int*)wp;  wp += (size_t)MAX_NB * sizeof(int);
    int* bucket_base   = (int*)wp;  wp += (size_t)(MAX_NB + 1) * sizeof(int);
    int* bucket_cursor = (int*)wp;  wp += (size_t)MAX_NB * sizeof(int);

    const int ROWS_PER_BLK = (BLK / 64) * 8;  // 32

    // ---------------- user-item graph ----------------
    {
        // UI CSR scratch lives in the uu_sum region of d_out (dead during UI phase).
        char* p = (char*)uu_sum;
        GraphBufs UI;
        UI.col      = (int*)p;   p += (size_t)E_UI * sizeof(int);          // 12.8 MB
        UI.row_ptr  = (int*)p;   p += (size_t)(N_ALL + 1) * sizeof(int);   // 1.2 MB
        UI.cnt_out  = (int*)p;   p += (size_t)N_ALL * sizeof(int);         // 1.2 MB
        UI.rsq_out  = (float*)p; p += (size_t)N_ALL * sizeof(float);       // 1.2 MB
        UI.rsq_in   = (float*)p; p += (size_t)N_ALL * sizeof(float);       // 1.2 MB
        UI.bucket_cnt = bucket_cnt;
        UI.bucket_base = bucket_base;
        UI.bucket_cursor = bucket_cursor;
        UI.binned = binned;

        build_graph(ui_src, ui_dst, E_UI, N_ALL, NB_UI, UI, stream);

        size_t tot = (size_t)N_ALL * D;
        init_ui_kernel<<<cdiv((int)tot, BLK), BLK, 0, stream>>>(
            user_emb, item_emb, UI.rsq_out, embA);

        bf16* bufs[2] = {embA, embB};
        for (int l = 0; l < 3; ++l) {
            const float* bA = (l == 0) ? user_emb : nullptr;
            const float* bB = (l == 0) ? item_emb : nullptr;
            gcn_layer_kernel<<<cdiv(N_ALL, ROWS_PER_BLK), BLK, 0, stream>>>(
                UI.row_ptr, UI.col, bufs[l & 1], UI.rsq_in, UI.rsq_out,
                bA, bB, (long)N_USER * D,
                ui_sum, bufs[(l + 1) & 1], N_ALL);
        }
    }

    // ---------------- user-user graph ----------------
    {
        GraphBufs UU;
        UU.col = uu_col;
        UU.row_ptr = uu_row_ptr;
        UU.cnt_out = uu_cnt_out;
        UU.rsq_out = uu_rsq_out;
        UU.rsq_in = uu_rsq_in;
        UU.bucket_cnt = bucket_cnt;
        UU.bucket_base = bucket_base;
        UU.bucket_cursor = bucket_cursor;
        UU.binned = binned;   // reuse (only first E_UU entries)

        build_graph(uu_src, uu_dst, E_UU, N_USER, NB_UU, UU, stream);

        size_t tot = (size_t)N_USER * D;
        init_uu_kernel<<<cdiv((int)tot, BLK), BLK, 0, stream>>>(
            user_emb, UU.rsq_out, embA);

        bf16* bufs[2] = {embA, embB};
        for (int l = 0; l < 2; ++l) {
            const float* bA = (l == 0) ? user_emb : nullptr;
            gcn_layer_kernel<<<cdiv(N_USER, ROWS_PER_BLK), BLK, 0, stream>>>(
                UU.row_ptr, UU.col, bufs[l & 1], UU.rsq_in, UU.rsq_out,
                bA, nullptr, (long)N_USER * D,
                uu_sum, bufs[(l + 1) & 1], N_USER);
        }
    }
}

// Round 6
// 672.705 us; speedup vs baseline: 5.3051x; 1.1703x over previous
//
#include <hip/hip_runtime.h>
#include <hip/hip_bf16.h>

constexpr int N_USER = 100000;
constexpr int N_ITEM = 200000;
constexpr int N_ALL  = N_USER + N_ITEM;
constexpr int E_UI   = 3200000;
constexpr int E_UU   = 1600000;
constexpr int D      = 64;
constexpr int BLK    = 256;

// bucketing: 512 rows per bucket
constexpr int RPB_SHIFT = 9;
constexpr int RPB       = 1 << RPB_SHIFT;   // 512
constexpr int MAX_NB    = 1024;             // >= cdiv(N_ALL, RPB) = 586

// bin_scatter tile geometry
constexpr int SBLK = 512;
constexpr int EPT  = 16;
constexpr int TILE = SBLK * EPT;            // 8192 edges per block

typedef __hip_bfloat16 bf16;

// ---------------- small helpers ----------------

__device__ inline int wave_incl_scan(int x, int lane) {
    #pragma unroll
    for (int off = 1; off < 64; off <<= 1) {
        int y = __shfl_up(x, off, 64);
        if (lane >= off) x += y;
    }
    return x;
}

static inline int cdiv(int a, int b) { return (a + b - 1) / b; }

// ---------------- init kernels (scaled bf16 emb only; sums fused into layer 1) ----------------

__global__ void init_ui_kernel(const float* __restrict__ ue,
                               const float* __restrict__ ie,
                               const float* __restrict__ rsq_out,
                               bf16* __restrict__ emb_scaled) {
    size_t t = (size_t)blockIdx.x * blockDim.x + threadIdx.x;
    const size_t total = (size_t)N_ALL * D;
    if (t >= total) return;
    const size_t userN = (size_t)N_USER * D;
    float v = (t < userN) ? ue[t] : ie[t - userN];
    int row = (int)(t >> 6);
    emb_scaled[t] = __float2bfloat16(v * rsq_out[row]);
}

__global__ void init_uu_kernel(const float* __restrict__ ue,
                               const float* __restrict__ rsq_out,
                               bf16* __restrict__ emb_scaled) {
    size_t t = (size_t)blockIdx.x * blockDim.x + threadIdx.x;
    const size_t total = (size_t)N_USER * D;
    if (t >= total) return;
    float v = ue[t];
    int row = (int)(t >> 6);
    emb_scaled[t] = __float2bfloat16(v * rsq_out[row]);
}

// ---------------- bucket histograms (both sides in one pass) ----------------

__global__ void bucket_hist2_kernel(const int* __restrict__ dst,
                                    const int* __restrict__ src, int E, int nb,
                                    int* __restrict__ bcntD_g,
                                    int* __restrict__ bcntS_g) {
    __shared__ int cD[MAX_NB];
    __shared__ int cS[MAX_NB];
    for (int b = threadIdx.x; b < nb; b += blockDim.x) { cD[b] = 0; cS[b] = 0; }
    __syncthreads();
    for (int e = blockIdx.x * blockDim.x + threadIdx.x; e < E;
         e += gridDim.x * blockDim.x) {
        atomicAdd(&cD[dst[e] >> RPB_SHIFT], 1);
        atomicAdd(&cS[src[e] >> RPB_SHIFT], 1);
    }
    __syncthreads();
    for (int b = threadIdx.x; b < nb; b += blockDim.x) {
        if (cD[b]) atomicAdd(&bcntD_g[b], cD[b]);
        if (cS[b]) atomicAdd(&bcntS_g[b], cS[b]);
    }
}

// ---------------- single-block exclusive scans (dst + src in one launch) ----------------

__device__ void scan_one(const int* __restrict__ cnt, int nb,
                         int* __restrict__ base, int* __restrict__ cursor,
                         int* wsum, int* carry_s) {
    int t = threadIdx.x, lane = t & 63, wid = t >> 6;
    if (t == 0) *carry_s = 0;
    for (int b0 = 0; b0 < nb; b0 += BLK) {
        __syncthreads();
        int i = b0 + t;
        int x = (i < nb) ? cnt[i] : 0;
        int s = wave_incl_scan(x, lane);
        if (lane == 63) wsum[wid] = s;
        __syncthreads();
        int add = *carry_s;
        for (int w = 0; w < wid; ++w) add += wsum[w];
        int excl = add + s - x;
        if (i < nb) { base[i] = excl; cursor[i] = excl; }
        int total = wsum[0] + wsum[1] + wsum[2] + wsum[3];
        __syncthreads();
        if (t == 0) *carry_s = add + total;  // add == old carry for t0
    }
    __syncthreads();
    if (t == 0) base[nb] = *carry_s;
    __syncthreads();
}

__global__ void scan2_buckets_kernel(const int* __restrict__ cntD, int nb,
                                     int* __restrict__ baseD, int* __restrict__ curD,
                                     const int* __restrict__ cntS,
                                     int* __restrict__ baseS, int* __restrict__ curS) {
    __shared__ int wsum[4];
    __shared__ int carry_s;
    scan_one(cntD, nb, baseD, curD, wsum, &carry_s);
    scan_one(cntS, nb, baseS, curS, wsum, &carry_s);
}

// ---------------- bin scatter: src IDs -> bucket-contiguous ----------------

__global__ __launch_bounds__(SBLK) void bin_scatter_src_kernel(
    const int* __restrict__ src, int E, int nb,
    int* __restrict__ cursor, int* __restrict__ binned_src) {
    __shared__ int bcnt[MAX_NB];
    __shared__ int bbase[MAX_NB];
    int t = threadIdx.x;
    for (int b = t; b < nb; b += SBLK) bcnt[b] = 0;
    __syncthreads();
    int base_e = blockIdx.x * TILE;
    int myk[EPT], myr[EPT];
    #pragma unroll
    for (int j = 0; j < EPT; ++j) {
        int e = base_e + j * SBLK + t;
        if (e < E) {
            int s = src[e];
            myk[j] = s;
            myr[j] = atomicAdd(&bcnt[s >> RPB_SHIFT], 1);
        } else {
            myk[j] = -1;
        }
    }
    __syncthreads();
    for (int b = t; b < nb; b += SBLK)
        if (bcnt[b] > 0) bbase[b] = atomicAdd(&cursor[b], bcnt[b]);
    __syncthreads();
    #pragma unroll
    for (int j = 0; j < EPT; ++j) {
        if (myk[j] >= 0)
            binned_src[bbase[myk[j] >> RPB_SHIFT] + myr[j]] = myk[j];
    }
}

// ---------------- per-bucket out-degree -> rsq_out (coalesced) ----------------

__global__ void bucket_rsq_kernel(const int* __restrict__ binned_src,
                                  const int* __restrict__ base, int n,
                                  float* __restrict__ rsq_out) {
    __shared__ int deg[RPB];
    int b = blockIdx.x;
    int row0 = b << RPB_SHIFT;
    int t = threadIdx.x;
    deg[t] = 0;
    deg[t + BLK] = 0;
    __syncthreads();
    int beg = base[b], end = base[b + 1];
    for (int e = beg + t; e < end; e += BLK)
        atomicAdd(&deg[binned_src[e] - row0], 1);
    __syncthreads();
    if (row0 + t < n)
        rsq_out[row0 + t] = 1.0f / sqrtf(fmaxf((float)deg[t], 1.0f));
    if (row0 + t + BLK < n)
        rsq_out[row0 + t + BLK] = 1.0f / sqrtf(fmaxf((float)deg[t + BLK], 1.0f));
}

// ---------------- bin scatter: edges -> bucket-contiguous (dst,src) pairs ----------------

__global__ __launch_bounds__(SBLK) void bin_scatter_kernel(
    const int* __restrict__ src, const int* __restrict__ dst, int E, int nb,
    int* __restrict__ cursor, int2* __restrict__ binned) {
    __shared__ int bcnt[MAX_NB];
    __shared__ int bbase[MAX_NB];
    int t = threadIdx.x;
    for (int b = t; b < nb; b += SBLK) bcnt[b] = 0;
    __syncthreads();
    int base_e = blockIdx.x * TILE;
    int myd[EPT], mys[EPT], myr[EPT];
    #pragma unroll
    for (int j = 0; j < EPT; ++j) {
        int e = base_e + j * SBLK + t;
        if (e < E) {
            int d = dst[e];
            mys[j] = src[e];
            myd[j] = d;
            myr[j] = atomicAdd(&bcnt[d >> RPB_SHIFT], 1);
        } else {
            myd[j] = -1;
        }
    }
    __syncthreads();
    for (int b = t; b < nb; b += SBLK)
        if (bcnt[b] > 0) bbase[b] = atomicAdd(&cursor[b], bcnt[b]);
    __syncthreads();
    #pragma unroll
    for (int j = 0; j < EPT; ++j) {
        if (myd[j] >= 0) {
            int b = myd[j] >> RPB_SHIFT;
            binned[bbase[b] + myr[j]] = make_int2(myd[j], mys[j]);
        }
    }
}

// ---------------- per-bucket CSR finalize ----------------

__global__ void bucket_csr_kernel(const int2* __restrict__ binned,
                                  const int* __restrict__ base, int nb, int n,
                                  int* __restrict__ row_ptr,
                                  float* __restrict__ rsq_in,
                                  int* __restrict__ col) {
    __shared__ int deg[RPB];
    __shared__ int cur[RPB];
    __shared__ int wsum[4];
    int b = blockIdx.x;
    int row0 = b << RPB_SHIFT;
    int nrows = min(RPB, n - row0);
    int t = threadIdx.x, lane = t & 63, wid = t >> 6;
    int beg = base[b], end = base[b + 1];

    deg[t] = 0;
    deg[t + BLK] = 0;
    __syncthreads();

    for (int e = beg + t; e < end; e += BLK)
        atomicAdd(&deg[binned[e].x - row0], 1);
    __syncthreads();

    // exclusive scan of deg[0..512) with 256 threads, two passes
    int x0 = deg[t];
    int s0 = wave_incl_scan(x0, lane);
    if (lane == 63) wsum[wid] = s0;
    __syncthreads();
    int add0 = 0;
    for (int w = 0; w < wid; ++w) add0 += wsum[w];
    int incl0 = s0 + add0;
    int tot0 = wsum[0] + wsum[1] + wsum[2] + wsum[3];
    __syncthreads();  // protect wsum before pass 2

    int x1 = deg[t + BLK];
    int s1 = wave_incl_scan(x1, lane);
    if (lane == 63) wsum[wid] = s1;
    __syncthreads();
    int add1 = 0;
    for (int w = 0; w < wid; ++w) add1 += wsum[w];
    int incl1 = s1 + add1;

    int excl0 = incl0 - x0;
    int excl1 = tot0 + incl1 - x1;
    cur[t] = beg + excl0;
    cur[t + BLK] = beg + excl1;
    if (t < nrows) {
        row_ptr[row0 + t] = beg + excl0;
        rsq_in[row0 + t] = 1.0f / sqrtf(fmaxf((float)x0, 1.0f));
    }
    if (t + BLK < nrows) {
        row_ptr[row0 + t + BLK] = beg + excl1;
        rsq_in[row0 + t + BLK] = 1.0f / sqrtf(fmaxf((float)x1, 1.0f));
    }
    if (b == nb - 1 && t == 0) row_ptr[n] = end;
    __syncthreads();

    for (int e = beg + t; e < end; e += BLK) {
        int2 p = binned[e];
        int pos = atomicAdd(&cur[p.x - row0], 1);
        col[pos] = p.y;
    }
}

// ---------------- fused GCN layer: 8 rows/wave, 8 lanes/row ----------------

__global__ void gcn_layer_kernel(const int* __restrict__ row_ptr,
                                 const int* __restrict__ col,
                                 const bf16* __restrict__ emb_in,
                                 const float* __restrict__ rsq_in,
                                 const float* __restrict__ rsq_out,
                                 const float* __restrict__ baseA,
                                 const float* __restrict__ baseB,
                                 long splitElems,
                                 float* __restrict__ sum_out,
                                 bf16* __restrict__ emb_out,
                                 int n) {
    int wave = blockIdx.x * (blockDim.x >> 6) + (threadIdx.x >> 6);
    int lane = threadIdx.x & 63;
    int q = lane & 7;                 // dim chunk
    int row = wave * 8 + (lane >> 3); // row slot
    bool act = row < n;
    int beg = 0, end = 0;
    if (act) { beg = row_ptr[row]; end = row_ptr[row + 1]; }

    float acc[8];
    #pragma unroll
    for (int k = 0; k < 8; ++k) acc[k] = 0.f;

    const int4* __restrict__ embv = (const int4*)emb_in;  // row s, chunk q at s*8+q

    int e = beg;
    for (; e + 2 <= end; e += 2) {
        int s0 = col[e];
        int s1 = col[e + 1];
        int4 w0 = embv[(size_t)s0 * 8 + q];
        int4 w1 = embv[(size_t)s1 * 8 + q];
        acc[0] += __int_as_float(w0.x << 16);
        acc[1] += __int_as_float(w0.x & 0xffff0000);
        acc[2] += __int_as_float(w0.y << 16);
        acc[3] += __int_as_float(w0.y & 0xffff0000);
        acc[4] += __int_as_float(w0.z << 16);
        acc[5] += __int_as_float(w0.z & 0xffff0000);
        acc[6] += __int_as_float(w0.w << 16);
        acc[7] += __int_as_float(w0.w & 0xffff0000);
        acc[0] += __int_as_float(w1.x << 16);
        acc[1] += __int_as_float(w1.x & 0xffff0000);
        acc[2] += __int_as_float(w1.y << 16);
        acc[3] += __int_as_float(w1.y & 0xffff0000);
        acc[4] += __int_as_float(w1.z << 16);
        acc[5] += __int_as_float(w1.z & 0xffff0000);
        acc[6] += __int_as_float(w1.w << 16);
        acc[7] += __int_as_float(w1.w & 0xffff0000);
    }
    if (e < end) {
        int s0 = col[e];
        int4 w0 = embv[(size_t)s0 * 8 + q];
        acc[0] += __int_as_float(w0.x << 16);
        acc[1] += __int_as_float(w0.x & 0xffff0000);
        acc[2] += __int_as_float(w0.y << 16);
        acc[3] += __int_as_float(w0.y & 0xffff0000);
        acc[4] += __int_as_float(w0.z << 16);
        acc[5] += __int_as_float(w0.z & 0xffff0000);
        acc[6] += __int_as_float(w0.w << 16);
        acc[7] += __int_as_float(w0.w & 0xffff0000);
    }

    float rin = act ? rsq_in[row] : 0.f;
    float vv[8];
    float ss = 0.f;
    #pragma unroll
    for (int k = 0; k < 8; ++k) {
        float v = acc[k] * rin;
        v = (v > 0.f) ? v : 0.5f * v;   // LeakyReLU(0.5)
        vv[k] = v;
        ss += v * v;
    }
    // L2-norm reduce across the 8 lanes of this row (xor within the group)
    ss += __shfl_xor(ss, 1, 64);
    ss += __shfl_xor(ss, 2, 64);
    ss += __shfl_xor(ss, 4, 64);
    float inv = 1.0f / fmaxf(sqrtf(ss), 1e-12f);

    if (act) {
        size_t o = (size_t)row * D + (size_t)q * 8;
        float base[8];
        if (baseA) {
            #pragma unroll
            for (int k = 0; k < 8; ++k) {
                size_t oo = o + k;
                base[k] = (oo < (size_t)splitElems) ? baseA[oo]
                                                    : baseB[oo - splitElems];
            }
        } else {
            const float4* sp = (const float4*)(sum_out + o);
            float4 b0 = sp[0], b1 = sp[1];
            base[0] = b0.x; base[1] = b0.y; base[2] = b0.z; base[3] = b0.w;
            base[4] = b1.x; base[5] = b1.y; base[6] = b1.z; base[7] = b1.w;
        }
        float4 o0, o1;
        o0.x = base[0] + vv[0] * inv;
        o0.y = base[1] + vv[1] * inv;
        o0.z = base[2] + vv[2] * inv;
        o0.w = base[3] + vv[3] * inv;
        o1.x = base[4] + vv[4] * inv;
        o1.y = base[5] + vv[5] * inv;
        o1.z = base[6] + vv[6] * inv;
        o1.w = base[7] + vv[7] * inv;
        float4* op = (float4*)(sum_out + o);
        op[0] = o0;
        op[1] = o1;

        float ro = rsq_out[row];
        union { int4 i4; bf16 h[8]; } pk;
        #pragma unroll
        for (int k = 0; k < 8; ++k) pk.h[k] = __float2bfloat16(vv[k] * ro);
        *(int4*)(emb_out + o) = pk.i4;
    }
}

// ---------------- host side ----------------

struct GraphBufs {
    int *col, *row_ptr;
    float *rsq_out, *rsq_in;
    int *bcnt_dst, *bcnt_src;           // contiguous pair for one memset
    int *base_dst, *base_src, *cur_dst, *cur_src;
    int2 *binned;
    int *binned_src;                    // aliases first half of binned
};

static void build_graph(const int* src, const int* dst, int E, int n, int nb,
                        GraphBufs& B, hipStream_t stream) {
    hipMemsetAsync(B.bcnt_dst, 0, 2 * (size_t)MAX_NB * sizeof(int), stream);
    bucket_hist2_kernel<<<512, BLK, 0, stream>>>(dst, src, E, nb,
                                                 B.bcnt_dst, B.bcnt_src);
    scan2_buckets_kernel<<<1, BLK, 0, stream>>>(B.bcnt_dst, nb, B.base_dst, B.cur_dst,
                                                B.bcnt_src, B.base_src, B.cur_src);
    bin_scatter_src_kernel<<<cdiv(E, TILE), SBLK, 0, stream>>>(
        src, E, nb, B.cur_src, B.binned_src);
    bucket_rsq_kernel<<<nb, BLK, 0, stream>>>(B.binned_src, B.base_src, n, B.rsq_out);
    bin_scatter_kernel<<<cdiv(E, TILE), SBLK, 0, stream>>>(
        src, dst, E, nb, B.cur_dst, B.binned);
    bucket_csr_kernel<<<nb, BLK, 0, stream>>>(B.binned, B.base_dst, nb, n,
                                              B.row_ptr, B.rsq_in, B.col);
}

extern "C" void kernel_launch(void* const* d_in, const int* in_sizes, int n_in,
                              void* d_out, int out_size, void* d_ws, size_t ws_size,
                              hipStream_t stream) {
    const float* user_emb = (const float*)d_in[0];
    const float* item_emb = (const float*)d_in[1];
    const int*   ui_src   = (const int*)d_in[2];
    const int*   ui_dst   = (const int*)d_in[3];
    const int*   uu_src   = (const int*)d_in[4];
    const int*   uu_dst   = (const int*)d_in[5];

    float* out    = (float*)d_out;
    float* ui_sum = out;                          // [N_ALL * D]
    float* uu_sum = out + (size_t)N_ALL * D;      // [N_USER * D]

    const int NB_UI = cdiv(N_ALL, RPB);   // 586
    const int NB_UU = cdiv(N_USER, RPB);  // 196

    // ws layout: embA | embB | binned (E_UI int2) | UU scratch | bucket arrays
    char* wp = (char*)d_ws;
    bf16* embA = (bf16*)wp;  wp += (size_t)N_ALL * D * sizeof(bf16);   // 38.4 MB
    bf16* embB = (bf16*)wp;  wp += (size_t)N_ALL * D * sizeof(bf16);   // 38.4 MB
    int2* binned = (int2*)wp; wp += (size_t)E_UI * sizeof(int2);       // 25.6 MB
    // UU scratch (used only in UU phase)
    int*   uu_col     = (int*)wp;   wp += (size_t)E_UU * sizeof(int);        // 6.4 MB
    int*   uu_row_ptr = (int*)wp;   wp += (size_t)(N_USER + 1) * sizeof(int);
    float* uu_rsq_out = (float*)wp; wp += (size_t)N_USER * sizeof(float);
    float* uu_rsq_in  = (float*)wp; wp += (size_t)N_USER * sizeof(float);
    // shared small bucket arrays
    int* bcnt_dst = (int*)wp;  wp += (size_t)MAX_NB * sizeof(int);
    int* bcnt_src = (int*)wp;  wp += (size_t)MAX_NB * sizeof(int);
    int* base_dst = (int*)wp;  wp += (size_t)(MAX_NB + 1) * sizeof(int);
    int* base_src = (int*)wp;  wp += (size_t)(MAX_NB + 1) * sizeof(int);
    int* cur_dst  = (int*)wp;  wp += (size_t)MAX_NB * sizeof(int);
    int* cur_src  = (int*)wp;  wp += (size_t)MAX_NB * sizeof(int);

    const int ROWS_PER_BLK = (BLK / 64) * 8;  // 32

    // ---------------- user-item graph ----------------
    {
        // UI CSR scratch lives in the uu_sum region of d_out (dead during UI phase).
        char* p = (char*)uu_sum;
        GraphBufs UI;
        UI.col      = (int*)p;   p += (size_t)E_UI * sizeof(int);          // 12.8 MB
        UI.row_ptr  = (int*)p;   p += (size_t)(N_ALL + 1) * sizeof(int);   // 1.2 MB
        UI.rsq_out  = (float*)p; p += (size_t)N_ALL * sizeof(float);       // 1.2 MB
        UI.rsq_in   = (float*)p; p += (size_t)N_ALL * sizeof(float);       // 1.2 MB
        UI.bcnt_dst = bcnt_dst; UI.bcnt_src = bcnt_src;
        UI.base_dst = base_dst; UI.base_src = base_src;
        UI.cur_dst  = cur_dst;  UI.cur_src  = cur_src;
        UI.binned = binned;
        UI.binned_src = (int*)binned;   // alias: dead before bin_scatter(dst) runs

        build_graph(ui_src, ui_dst, E_UI, N_ALL, NB_UI, UI, stream);

        size_t tot = (size_t)N_ALL * D;
        init_ui_kernel<<<cdiv((int)tot, BLK), BLK, 0, stream>>>(
            user_emb, item_emb, UI.rsq_out, embA);

        bf16* bufs[2] = {embA, embB};
        for (int l = 0; l < 3; ++l) {
            const float* bA = (l == 0) ? user_emb : nullptr;
            const float* bB = (l == 0) ? item_emb : nullptr;
            gcn_layer_kernel<<<cdiv(N_ALL, ROWS_PER_BLK), BLK, 0, stream>>>(
                UI.row_ptr, UI.col, bufs[l & 1], UI.rsq_in, UI.rsq_out,
                bA, bB, (long)N_USER * D,
                ui_sum, bufs[(l + 1) & 1], N_ALL);
        }
    }

    // ---------------- user-user graph ----------------
    {
        GraphBufs UU;
        UU.col = uu_col;
        UU.row_ptr = uu_row_ptr;
        UU.rsq_out = uu_rsq_out;
        UU.rsq_in = uu_rsq_in;
        UU.bcnt_dst = bcnt_dst; UU.bcnt_src = bcnt_src;
        UU.base_dst = base_dst; UU.base_src = base_src;
        UU.cur_dst  = cur_dst;  UU.cur_src  = cur_src;
        UU.binned = binned;             // reuse (only first E_UU entries)
        UU.binned_src = (int*)binned;

        build_graph(uu_src, uu_dst, E_UU, N_USER, NB_UU, UU, stream);

        size_t tot = (size_t)N_USER * D;
        init_uu_kernel<<<cdiv((int)tot, BLK), BLK, 0, stream>>>(
            user_emb, UU.rsq_out, embA);

        bf16* bufs[2] = {embA, embB};
        for (int l = 0; l < 2; ++l) {
            const float* bA = (l == 0) ? user_emb : nullptr;
            gcn_layer_kernel<<<cdiv(N_USER, ROWS_PER_BLK), BLK, 0, stream>>>(
                UU.row_ptr, UU.col, bufs[l & 1], UU.rsq_in, UU.rsq_out,
                bA, nullptr, (long)N_USER * D,
                uu_sum, bufs[(l + 1) & 1], N_USER);
        }
    }
}

// Round 8
// 656.062 us; speedup vs baseline: 5.4397x; 1.0254x over previous
//
#include <hip/hip_runtime.h>
#include <hip/hip_bf16.h>

constexpr int N_USER = 100000;
constexpr int N_ITEM = 200000;
constexpr int N_ALL  = N_USER + N_ITEM;
constexpr int E_UI   = 3200000;
constexpr int E_UU   = 1600000;
constexpr int D      = 64;
constexpr int BLK    = 256;

// bucketing: 512 rows per bucket
constexpr int RPB_SHIFT = 9;
constexpr int RPB       = 1 << RPB_SHIFT;   // 512
constexpr int MAX_NB    = 1024;             // >= cdiv(N_ALL, RPB) = 586

// bin_scatter tile geometry
constexpr int SBLK = 512;
constexpr int EPT  = 16;
constexpr int TILE = SBLK * EPT;            // 8192 edges per block

typedef __hip_bfloat16 bf16;

// ---------------- small helpers ----------------

__device__ inline int wave_incl_scan(int x, int lane) {
    #pragma unroll
    for (int off = 1; off < 64; off <<= 1) {
        int y = __shfl_up(x, off, 64);
        if (lane >= off) x += y;
    }
    return x;
}

static inline int cdiv(int a, int b) { return (a + b - 1) / b; }

// accumulate 8 bf16 (packed in an int4) into 8 f32 accumulators
__device__ inline void acc8(float* acc, const int4 v) {
    acc[0] += __int_as_float(v.x << 16);
    acc[1] += __int_as_float(v.x & 0xffff0000);
    acc[2] += __int_as_float(v.y << 16);
    acc[3] += __int_as_float(v.y & 0xffff0000);
    acc[4] += __int_as_float(v.z << 16);
    acc[5] += __int_as_float(v.z & 0xffff0000);
    acc[6] += __int_as_float(v.w << 16);
    acc[7] += __int_as_float(v.w & 0xffff0000);
}

// ---------------- init kernels (scaled bf16 emb only; sums fused into layer 1) ----------------

__global__ void init_ui_kernel(const float* __restrict__ ue,
                               const float* __restrict__ ie,
                               const float* __restrict__ rsq_out,
                               bf16* __restrict__ emb_scaled) {
    size_t t = (size_t)blockIdx.x * blockDim.x + threadIdx.x;
    const size_t total = (size_t)N_ALL * D;
    if (t >= total) return;
    const size_t userN = (size_t)N_USER * D;
    float v = (t < userN) ? ue[t] : ie[t - userN];
    int row = (int)(t >> 6);
    emb_scaled[t] = __float2bfloat16(v * rsq_out[row]);
}

__global__ void init_uu_kernel(const float* __restrict__ ue,
                               const float* __restrict__ rsq_out,
                               bf16* __restrict__ emb_scaled) {
    size_t t = (size_t)blockIdx.x * blockDim.x + threadIdx.x;
    const size_t total = (size_t)N_USER * D;
    if (t >= total) return;
    float v = ue[t];
    int row = (int)(t >> 6);
    emb_scaled[t] = __float2bfloat16(v * rsq_out[row]);
}

// ---------------- bucket histograms (both sides in one pass) ----------------

__global__ void bucket_hist2_kernel(const int* __restrict__ dst,
                                    const int* __restrict__ src, int E, int nb,
                                    int* __restrict__ bcntD_g,
                                    int* __restrict__ bcntS_g) {
    __shared__ int cD[MAX_NB];
    __shared__ int cS[MAX_NB];
    for (int b = threadIdx.x; b < nb; b += blockDim.x) { cD[b] = 0; cS[b] = 0; }
    __syncthreads();
    for (int e = blockIdx.x * blockDim.x + threadIdx.x; e < E;
         e += gridDim.x * blockDim.x) {
        atomicAdd(&cD[dst[e] >> RPB_SHIFT], 1);
        atomicAdd(&cS[src[e] >> RPB_SHIFT], 1);
    }
    __syncthreads();
    for (int b = threadIdx.x; b < nb; b += blockDim.x) {
        if (cD[b]) atomicAdd(&bcntD_g[b], cD[b]);
        if (cS[b]) atomicAdd(&bcntS_g[b], cS[b]);
    }
}

// ---------------- single-block exclusive scans (dst + src in one launch) ----------------

__device__ void scan_one(const int* __restrict__ cnt, int nb,
                         int* __restrict__ base, int* __restrict__ cursor,
                         int* wsum, int* carry_s) {
    int t = threadIdx.x, lane = t & 63, wid = t >> 6;
    if (t == 0) *carry_s = 0;
    for (int b0 = 0; b0 < nb; b0 += BLK) {
        __syncthreads();
        int i = b0 + t;
        int x = (i < nb) ? cnt[i] : 0;
        int s = wave_incl_scan(x, lane);
        if (lane == 63) wsum[wid] = s;
        __syncthreads();
        int add = *carry_s;
        for (int w = 0; w < wid; ++w) add += wsum[w];
        int excl = add + s - x;
        if (i < nb) { base[i] = excl; cursor[i] = excl; }
        int total = wsum[0] + wsum[1] + wsum[2] + wsum[3];
        __syncthreads();
        if (t == 0) *carry_s = add + total;  // add == old carry for t0
    }
    __syncthreads();
    if (t == 0) base[nb] = *carry_s;
    __syncthreads();
}

__global__ void scan2_buckets_kernel(const int* __restrict__ cntD, int nb,
                                     int* __restrict__ baseD, int* __restrict__ curD,
                                     const int* __restrict__ cntS,
                                     int* __restrict__ baseS, int* __restrict__ curS) {
    __shared__ int wsum[4];
    __shared__ int carry_s;
    scan_one(cntD, nb, baseD, curD, wsum, &carry_s);
    scan_one(cntS, nb, baseS, curS, wsum, &carry_s);
}

// ---------------- bin scatter: src IDs -> bucket-contiguous ----------------

__global__ __launch_bounds__(SBLK) void bin_scatter_src_kernel(
    const int* __restrict__ src, int E, int nb,
    int* __restrict__ cursor, int* __restrict__ binned_src) {
    __shared__ int bcnt[MAX_NB];
    __shared__ int bbase[MAX_NB];
    int t = threadIdx.x;
    for (int b = t; b < nb; b += SBLK) bcnt[b] = 0;
    __syncthreads();
    int base_e = blockIdx.x * TILE;
    int myk[EPT], myr[EPT];
    #pragma unroll
    for (int j = 0; j < EPT; ++j) {
        int e = base_e + j * SBLK + t;
        if (e < E) {
            int s = src[e];
            myk[j] = s;
            myr[j] = atomicAdd(&bcnt[s >> RPB_SHIFT], 1);
        } else {
            myk[j] = -1;
        }
    }
    __syncthreads();
    for (int b = t; b < nb; b += SBLK)
        if (bcnt[b] > 0) bbase[b] = atomicAdd(&cursor[b], bcnt[b]);
    __syncthreads();
    #pragma unroll
    for (int j = 0; j < EPT; ++j) {
        if (myk[j] >= 0)
            binned_src[bbase[myk[j] >> RPB_SHIFT] + myr[j]] = myk[j];
    }
}

// ---------------- per-bucket out-degree -> rsq_out (coalesced) ----------------

__global__ void bucket_rsq_kernel(const int* __restrict__ binned_src,
                                  const int* __restrict__ base, int n,
                                  float* __restrict__ rsq_out) {
    __shared__ int deg[RPB];
    int b = blockIdx.x;
    int row0 = b << RPB_SHIFT;
    int t = threadIdx.x;
    deg[t] = 0;
    deg[t + BLK] = 0;
    __syncthreads();
    int beg = base[b], end = base[b + 1];
    for (int e = beg + t; e < end; e += BLK)
        atomicAdd(&deg[binned_src[e] - row0], 1);
    __syncthreads();
    if (row0 + t < n)
        rsq_out[row0 + t] = 1.0f / sqrtf(fmaxf((float)deg[t], 1.0f));
    if (row0 + t + BLK < n)
        rsq_out[row0 + t + BLK] = 1.0f / sqrtf(fmaxf((float)deg[t + BLK], 1.0f));
}

// ---------------- bin scatter: edges -> bucket-contiguous (dst,src) pairs ----------------

__global__ __launch_bounds__(SBLK) void bin_scatter_kernel(
    const int* __restrict__ src, const int* __restrict__ dst, int E, int nb,
    int* __restrict__ cursor, int2* __restrict__ binned) {
    __shared__ int bcnt[MAX_NB];
    __shared__ int bbase[MAX_NB];
    int t = threadIdx.x;
    for (int b = t; b < nb; b += SBLK) bcnt[b] = 0;
    __syncthreads();
    int base_e = blockIdx.x * TILE;
    int myd[EPT], mys[EPT], myr[EPT];
    #pragma unroll
    for (int j = 0; j < EPT; ++j) {
        int e = base_e + j * SBLK + t;
        if (e < E) {
            int d = dst[e];
            mys[j] = src[e];
            myd[j] = d;
            myr[j] = atomicAdd(&bcnt[d >> RPB_SHIFT], 1);
        } else {
            myd[j] = -1;
        }
    }
    __syncthreads();
    for (int b = t; b < nb; b += SBLK)
        if (bcnt[b] > 0) bbase[b] = atomicAdd(&cursor[b], bcnt[b]);
    __syncthreads();
    #pragma unroll
    for (int j = 0; j < EPT; ++j) {
        if (myd[j] >= 0) {
            int b = myd[j] >> RPB_SHIFT;
            binned[bbase[b] + myr[j]] = make_int2(myd[j], mys[j]);
        }
    }
}

// ---------------- per-bucket CSR finalize ----------------

__global__ void bucket_csr_kernel(const int2* __restrict__ binned,
                                  const int* __restrict__ base, int nb, int n,
                                  int* __restrict__ row_ptr,
                                  float* __restrict__ rsq_in,
                                  int* __restrict__ col) {
    __shared__ int deg[RPB];
    __shared__ int cur[RPB];
    __shared__ int wsum[4];
    int b = blockIdx.x;
    int row0 = b << RPB_SHIFT;
    int nrows = min(RPB, n - row0);
    int t = threadIdx.x, lane = t & 63, wid = t >> 6;
    int beg = base[b], end = base[b + 1];

    deg[t] = 0;
    deg[t + BLK] = 0;
    __syncthreads();

    for (int e = beg + t; e < end; e += BLK)
        atomicAdd(&deg[binned[e].x - row0], 1);
    __syncthreads();

    // exclusive scan of deg[0..512) with 256 threads, two passes
    int x0 = deg[t];
    int s0 = wave_incl_scan(x0, lane);
    if (lane == 63) wsum[wid] = s0;
    __syncthreads();
    int add0 = 0;
    for (int w = 0; w < wid; ++w) add0 += wsum[w];
    int incl0 = s0 + add0;
    int tot0 = wsum[0] + wsum[1] + wsum[2] + wsum[3];
    __syncthreads();  // protect wsum before pass 2

    int x1 = deg[t + BLK];
    int s1 = wave_incl_scan(x1, lane);
    if (lane == 63) wsum[wid] = s1;
    __syncthreads();
    int add1 = 0;
    for (int w = 0; w < wid; ++w) add1 += wsum[w];
    int incl1 = s1 + add1;

    int excl0 = incl0 - x0;
    int excl1 = tot0 + incl1 - x1;
    cur[t] = beg + excl0;
    cur[t + BLK] = beg + excl1;
    if (t < nrows) {
        row_ptr[row0 + t] = beg + excl0;
        rsq_in[row0 + t] = 1.0f / sqrtf(fmaxf((float)x0, 1.0f));
    }
    if (t + BLK < nrows) {
        row_ptr[row0 + t + BLK] = beg + excl1;
        rsq_in[row0 + t + BLK] = 1.0f / sqrtf(fmaxf((float)x1, 1.0f));
    }
    if (b == nb - 1 && t == 0) row_ptr[n] = end;
    __syncthreads();

    for (int e = beg + t; e < end; e += BLK) {
        int2 p = binned[e];
        int pos = atomicAdd(&cur[p.x - row0], 1);
        col[pos] = p.y;
    }
}

// ---------------- fused GCN layer: 8 rows/wave, 8 lanes/row ----------------
// 4-deep unrolled gather for MLP (4 int4 loads in flight per wave).
// emb_out == nullptr on the final layer of each graph (output never read).

__global__ void gcn_layer_kernel(const int* __restrict__ row_ptr,
                                 const int* __restrict__ col,
                                 const bf16* __restrict__ emb_in,
                                 const float* __restrict__ rsq_in,
                                 const float* __restrict__ rsq_out,
                                 const float* __restrict__ baseA,
                                 const float* __restrict__ baseB,
                                 long splitElems,
                                 float* __restrict__ sum_out,
                                 bf16* __restrict__ emb_out,
                                 int n) {
    int wave = blockIdx.x * (blockDim.x >> 6) + (threadIdx.x >> 6);
    int lane = threadIdx.x & 63;
    int q = lane & 7;                 // dim chunk
    int row = wave * 8 + (lane >> 3); // row slot
    bool act = row < n;
    int beg = 0, end = 0;
    if (act) { beg = row_ptr[row]; end = row_ptr[row + 1]; }

    float acc[8];
    #pragma unroll
    for (int k = 0; k < 8; ++k) acc[k] = 0.f;

    const int4* __restrict__ embv = (const int4*)emb_in;  // row s, chunk q at s*8+q

    int e = beg;
    for (; e + 4 <= end; e += 4) {
        int s0 = col[e];
        int s1 = col[e + 1];
        int s2 = col[e + 2];
        int s3 = col[e + 3];
        int4 w0 = embv[(size_t)s0 * 8 + q];
        int4 w1 = embv[(size_t)s1 * 8 + q];
        int4 w2 = embv[(size_t)s2 * 8 + q];
        int4 w3 = embv[(size_t)s3 * 8 + q];
        acc8(acc, w0);
        acc8(acc, w1);
        acc8(acc, w2);
        acc8(acc, w3);
    }
    for (; e < end; ++e) {
        int s0 = col[e];
        int4 w0 = embv[(size_t)s0 * 8 + q];
        acc8(acc, w0);
    }

    float rin = act ? rsq_in[row] : 0.f;
    float vv[8];
    float ss = 0.f;
    #pragma unroll
    for (int k = 0; k < 8; ++k) {
        float v = acc[k] * rin;
        v = (v > 0.f) ? v : 0.5f * v;   // LeakyReLU(0.5)
        vv[k] = v;
        ss += v * v;
    }
    // L2-norm reduce across the 8 lanes of this row (xor within the group)
    ss += __shfl_xor(ss, 1, 64);
    ss += __shfl_xor(ss, 2, 64);
    ss += __shfl_xor(ss, 4, 64);
    float inv = 1.0f / fmaxf(sqrtf(ss), 1e-12f);

    if (act) {
        size_t o = (size_t)row * D + (size_t)q * 8;
        float base[8];
        if (baseA) {
            #pragma unroll
            for (int k = 0; k < 8; ++k) {
                size_t oo = o + k;
                base[k] = (oo < (size_t)splitElems) ? baseA[oo]
                                                    : baseB[oo - splitElems];
            }
        } else {
            const float4* sp = (const float4*)(sum_out + o);
            float4 b0 = sp[0], b1 = sp[1];
            base[0] = b0.x; base[1] = b0.y; base[2] = b0.z; base[3] = b0.w;
            base[4] = b1.x; base[5] = b1.y; base[6] = b1.z; base[7] = b1.w;
        }
        float4 o0, o1;
        o0.x = base[0] + vv[0] * inv;
        o0.y = base[1] + vv[1] * inv;
        o0.z = base[2] + vv[2] * inv;
        o0.w = base[3] + vv[3] * inv;
        o1.x = base[4] + vv[4] * inv;
        o1.y = base[5] + vv[5] * inv;
        o1.z = base[6] + vv[6] * inv;
        o1.w = base[7] + vv[7] * inv;
        float4* op = (float4*)(sum_out + o);
        op[0] = o0;
        op[1] = o1;

        if (emb_out) {
            float ro = rsq_out[row];
            union { int4 i4; bf16 h[8]; } pk;
            #pragma unroll
            for (int k = 0; k < 8; ++k) pk.h[k] = __float2bfloat16(vv[k] * ro);
            *(int4*)(emb_out + o) = pk.i4;
        }
    }
}

// ---------------- host side ----------------

struct GraphBufs {
    int *col, *row_ptr;
    float *rsq_out, *rsq_in;
    int *bcnt_dst, *bcnt_src;           // contiguous pair for one memset
    int *base_dst, *base_src, *cur_dst, *cur_src;
    int2 *binned;
    int *binned_src;                    // aliases first half of binned
};

static void build_graph(const int* src, const int* dst, int E, int n, int nb,
                        GraphBufs& B, hipStream_t stream) {
    (void)hipMemsetAsync(B.bcnt_dst, 0, 2 * (size_t)MAX_NB * sizeof(int), stream);
    bucket_hist2_kernel<<<512, BLK, 0, stream>>>(dst, src, E, nb,
                                                 B.bcnt_dst, B.bcnt_src);
    scan2_buckets_kernel<<<1, BLK, 0, stream>>>(B.bcnt_dst, nb, B.base_dst, B.cur_dst,
                                                B.bcnt_src, B.base_src, B.cur_src);
    bin_scatter_src_kernel<<<cdiv(E, TILE), SBLK, 0, stream>>>(
        src, E, nb, B.cur_src, B.binned_src);
    bucket_rsq_kernel<<<nb, BLK, 0, stream>>>(B.binned_src, B.base_src, n, B.rsq_out);
    bin_scatter_kernel<<<cdiv(E, TILE), SBLK, 0, stream>>>(
        src, dst, E, nb, B.cur_dst, B.binned);
    bucket_csr_kernel<<<nb, BLK, 0, stream>>>(B.binned, B.base_dst, nb, n,
                                              B.row_ptr, B.rsq_in, B.col);
}

extern "C" void kernel_launch(void* const* d_in, const int* in_sizes, int n_in,
                              void* d_out, int out_size, void* d_ws, size_t ws_size,
                              hipStream_t stream) {
    const float* user_emb = (const float*)d_in[0];
    const float* item_emb = (const float*)d_in[1];
    const int*   ui_src   = (const int*)d_in[2];
    const int*   ui_dst   = (const int*)d_in[3];
    const int*   uu_src   = (const int*)d_in[4];
    const int*   uu_dst   = (const int*)d_in[5];

    float* out    = (float*)d_out;
    float* ui_sum = out;                          // [N_ALL * D]
    float* uu_sum = out + (size_t)N_ALL * D;      // [N_USER * D]

    const int NB_UI = cdiv(N_ALL, RPB);   // 586
    const int NB_UU = cdiv(N_USER, RPB);  // 196

    // ws layout: embA | embB | binned (E_UI int2) | UU scratch | bucket arrays
    char* wp = (char*)d_ws;
    bf16* embA = (bf16*)wp;  wp += (size_t)N_ALL * D * sizeof(bf16);   // 38.4 MB
    bf16* embB = (bf16*)wp;  wp += (size_t)N_ALL * D * sizeof(bf16);   // 38.4 MB
    int2* binned = (int2*)wp; wp += (size_t)E_UI * sizeof(int2);       // 25.6 MB
    // UU scratch (used only in UU phase)
    int*   uu_col     = (int*)wp;   wp += (size_t)E_UU * sizeof(int);        // 6.4 MB
    int*   uu_row_ptr = (int*)wp;   wp += (size_t)(N_USER + 1) * sizeof(int);
    float* uu_rsq_out = (float*)wp; wp += (size_t)N_USER * sizeof(float);
    float* uu_rsq_in  = (float*)wp; wp += (size_t)N_USER * sizeof(float);
    // shared small bucket arrays
    int* bcnt_dst = (int*)wp;  wp += (size_t)MAX_NB * sizeof(int);
    int* bcnt_src = (int*)wp;  wp += (size_t)MAX_NB * sizeof(int);
    int* base_dst = (int*)wp;  wp += (size_t)(MAX_NB + 1) * sizeof(int);
    int* base_src = (int*)wp;  wp += (size_t)(MAX_NB + 1) * sizeof(int);
    int* cur_dst  = (int*)wp;  wp += (size_t)MAX_NB * sizeof(int);
    int* cur_src  = (int*)wp;  wp += (size_t)MAX_NB * sizeof(int);

    const int ROWS_PER_BLK = (BLK / 64) * 8;  // 32

    // ---------------- user-item graph ----------------
    {
        // UI CSR scratch lives in the uu_sum region of d_out (dead during UI phase).
        char* p = (char*)uu_sum;
        GraphBufs UI;
        UI.col      = (int*)p;   p += (size_t)E_UI * sizeof(int);          // 12.8 MB
        UI.row_ptr  = (int*)p;   p += (size_t)(N_ALL + 1) * sizeof(int);   // 1.2 MB
        UI.rsq_out  = (float*)p; p += (size_t)N_ALL * sizeof(float);       // 1.2 MB
        UI.rsq_in   = (float*)p; p += (size_t)N_ALL * sizeof(float);       // 1.2 MB
        UI.bcnt_dst = bcnt_dst; UI.bcnt_src = bcnt_src;
        UI.base_dst = base_dst; UI.base_src = base_src;
        UI.cur_dst  = cur_dst;  UI.cur_src  = cur_src;
        UI.binned = binned;
        UI.binned_src = (int*)binned;   // alias: dead before bin_scatter(dst) runs

        build_graph(ui_src, ui_dst, E_UI, N_ALL, NB_UI, UI, stream);

        size_t tot = (size_t)N_ALL * D;
        init_ui_kernel<<<cdiv((int)tot, BLK), BLK, 0, stream>>>(
            user_emb, item_emb, UI.rsq_out, embA);

        bf16* bufs[2] = {embA, embB};
        for (int l = 0; l < 3; ++l) {
            const float* bA = (l == 0) ? user_emb : nullptr;
            const float* bB = (l == 0) ? item_emb : nullptr;
            bf16* eout = (l == 2) ? nullptr : bufs[(l + 1) & 1];
            gcn_layer_kernel<<<cdiv(N_ALL, ROWS_PER_BLK), BLK, 0, stream>>>(
                UI.row_ptr, UI.col, bufs[l & 1], UI.rsq_in, UI.rsq_out,
                bA, bB, (long)N_USER * D,
                ui_sum, eout, N_ALL);
        }
    }

    // ---------------- user-user graph ----------------
    {
        GraphBufs UU;
        UU.col = uu_col;
        UU.row_ptr = uu_row_ptr;
        UU.rsq_out = uu_rsq_out;
        UU.rsq_in = uu_rsq_in;
        UU.bcnt_dst = bcnt_dst; UU.bcnt_src = bcnt_src;
        UU.base_dst = base_dst; UU.base_src = base_src;
        UU.cur_dst  = cur_dst;  UU.cur_src  = cur_src;
        UU.binned = binned;             // reuse (only first E_UU entries)
        UU.binned_src = (int*)binned;

        build_graph(uu_src, uu_dst, E_UU, N_USER, NB_UU, UU, stream);

        size_t tot = (size_t)N_USER * D;
        init_uu_kernel<<<cdiv((int)tot, BLK), BLK, 0, stream>>>(
            user_emb, UU.rsq_out, embA);

        bf16* bufs[2] = {embA, embB};
        for (int l = 0; l < 2; ++l) {
            const float* bA = (l == 0) ? user_emb : nullptr;
            bf16* eout = (l == 1) ? nullptr : bufs[(l + 1) & 1];
            gcn_layer_kernel<<<cdiv(N_USER, ROWS_PER_BLK), BLK, 0, stream>>>(
                UU.row_ptr, UU.col, bufs[l & 1], UU.rsq_in, UU.rsq_out,
                bA, nullptr, (long)N_USER * D,
                uu_sum, eout, N_USER);
        }
    }
}